// Round 10
// baseline (526.941 us; speedup 1.0000x reference)
//
#include <hip/hip_runtime.h>
#include <math.h>

namespace {
constexpr int NB   = 256;          // graphs
constexpr int EPG  = 8192;         // edges per graph
constexpr int ETOT = NB * EPG;     // 2,097,152
constexpr int FH   = 64;           // hidden dim
constexpr int NN0  = NB * 512;     // 131072 nodes at full size
}

// ---- scratch (device globals: write-before-read each call, deterministic) ----
__device__ float g_feat[3][(size_t)NN0 * FH];   // rotating node-feature buffers
__device__ float g_xs[NB * 6 * FH];             // jumping-knowledge concat
__device__ int   g_esrc[2][ETOT];               // compacted edges (stage 0/1)
__device__ int   g_edst[2][ETOT];
__device__ int   g_ecnt[2][NB];

// ============================================================================
// Dual matmul: zr = x@Wr ; xl = x@Wl + b   (x: [M,K], W: [K,64], M % 64 == 0)
// v5: 64-row blocks (grid x2, occupancy up); weights staged TRANSPOSED in LDS
// as [kq][64][4] so weight reads are ds_read_b128 (4 per k4 instead of 16 b32);
// per-thread 8 rows x 4 outputs. LDS 24KB -> 6 blocks/CU.
// ============================================================================
template<int K>
__global__ __launch_bounds__(256)
void mm_dual(const float* __restrict__ xext, int in_idx,
             const float* __restrict__ Wr, const float* __restrict__ Wl,
             const float* __restrict__ bias, int zr_idx, int xl_idx)
{
  constexpr int RPB = 64;           // rows per block
  constexpr int KC  = 32;           // k-chunk staged in LDS
  __shared__ float xs[RPB][KC];     // 8 KB
  __shared__ float wrT[KC/4][64][4];// 8 KB  (wrT[kq][c][i] = Wr[c0+kq*4+i][c])
  __shared__ float wlT[KC/4][64][4];// 8 KB
  const float* __restrict__ x = (in_idx < 0) ? xext : g_feat[in_idx];
  float* __restrict__ zr = g_feat[zr_idx];
  float* __restrict__ xl = g_feat[xl_idx];
  const int t = threadIdx.x;
  const int rowbase = blockIdx.x * RPB;
  const int f  = t & 31;            // output cols f, f+32 (both mats)
  const int rg = t >> 5;            // 8 row-groups x 8 rows
  const int wv = t >> 6;            // wave id (0..3)
  const int wc = t & 63;            // weight-stage col
  const int wq = t >> 6;            // weight-stage quad group (0..3)
  float ar0[8], ar1[8], al0[8], al1[8];
  #pragma unroll
  for (int r = 0; r < 8; ++r) { ar0[r]=0.f; ar1[r]=0.f; al0[r]=0.f; al1[r]=0.f; }

  for (int c = 0; c < K / KC; ++c) {
    __syncthreads();                       // WAR: previous chunk fully consumed
    #pragma unroll
    for (int i = 0; i < 2; ++i) {          // x: 512 slots of 16B = 8 KB
      const int idx = t + i * 256;
      const int r = idx >> 3, q = idx & 7;
      const float* gp = &x[(size_t)(rowbase + r) * K + c * KC + q * 4];
      float* lp = &xs[0][0] + (size_t)(i * 256 + wv * 64) * 4;
      __builtin_amdgcn_global_load_lds(
          (const __attribute__((address_space(1))) unsigned int*)gp,
          (__attribute__((address_space(3))) unsigned int*)lp, 16, 0, 0);
    }
    // weights, transposed: thread (wc, wq) fills kq = 2*wq, 2*wq+1
    #pragma unroll
    for (int h = 0; h < 2; ++h) {
      const int kq = wq * 2 + h;
      #pragma unroll
      for (int i = 0; i < 4; ++i) {
        const int krow = c * KC + kq * 4 + i;
        wrT[kq][wc][i] = Wr[(size_t)krow * 64 + wc];
        wlT[kq][wc][i] = Wl[(size_t)krow * 64 + wc];
      }
    }
    __syncthreads();                       // drains vmcnt/lgkm: LDS visible
    for (int k4 = 0; k4 < KC / 4; ++k4) {
      const float4 wr0 = *reinterpret_cast<const float4*>(&wrT[k4][f][0]);
      const float4 wr1 = *reinterpret_cast<const float4*>(&wrT[k4][f+32][0]);
      const float4 wl0 = *reinterpret_cast<const float4*>(&wlT[k4][f][0]);
      const float4 wl1 = *reinterpret_cast<const float4*>(&wlT[k4][f+32][0]);
      #pragma unroll
      for (int r = 0; r < 8; ++r) {
        const float4 xv = *reinterpret_cast<const float4*>(&xs[rg*8 + r][k4*4]);
        ar0[r] += xv.x*wr0.x + xv.y*wr0.y + xv.z*wr0.z + xv.w*wr0.w;
        ar1[r] += xv.x*wr1.x + xv.y*wr1.y + xv.z*wr1.z + xv.w*wr1.w;
        al0[r] += xv.x*wl0.x + xv.y*wl0.y + xv.z*wl0.z + xv.w*wl0.w;
        al1[r] += xv.x*wl1.x + xv.y*wl1.y + xv.z*wl1.z + xv.w*wl1.w;
      }
    }
  }
  const float bv0 = bias[f], bv1 = bias[f + 32];
  #pragma unroll
  for (int r = 0; r < 8; ++r) {
    const size_t row = (size_t)(rowbase + rg * 8 + r);
    zr[row * 64 + f]      = ar0[r];
    zr[row * 64 + f + 32] = ar1[r];
    xl[row * 64 + f]      = al0[r] + bv0;
    xl[row * 64 + f + 32] = al1[r] + bv1;
  }
}

// ============================================================================
// Full-size (n=512/graph) mean-aggregation + residual + relu + fused gmp.
// Gather unrolled x4 with independent accumulators (hide L2 latency).
// ============================================================================
__global__ __launch_bounds__(1024)
void agg_full(int zr_idx, int xl_idx,
              const int* __restrict__ esrc, const int* __restrict__ edst,
              int out_idx, int xs_off)
{
  __shared__ unsigned int hist[512], bufA[512], bufB[512];
  __shared__ unsigned short csr[EPG];
  __shared__ float red[16][64];
  const float* __restrict__ zr  = g_feat[zr_idx];
  const float* __restrict__ xlb = g_feat[xl_idx];
  float* __restrict__ xout = g_feat[out_idx];
  const int g = blockIdx.x, t = threadIdx.x;
  const int gbase = g * 512, ebase = g * EPG;
  for (int i = t; i < 512; i += 1024) hist[i] = 0;
  __syncthreads();
  for (int e = t; e < EPG; e += 1024)
    atomicAdd(&hist[edst[ebase + e] - gbase], 1u);
  __syncthreads();
  if (t < 512) bufA[t] = hist[t];
  __syncthreads();
  unsigned int *pa = bufA, *pb = bufB;
  for (int off = 1; off < 512; off <<= 1) {      // Hillis-Steele inclusive scan
    if (t < 512) {
      unsigned int v = pa[t];
      if (t >= off) v += pa[t - off];
      pb[t] = v;
    }
    __syncthreads();
    unsigned int* tmp = pa; pa = pb; pb = tmp;
  }
  unsigned int excl = 0;
  if (t < 512) excl = pa[t] - hist[t];
  __syncthreads();
  if (t < 512) { bufA[t] = excl; bufB[t] = excl; }  // bufA = start, bufB = cursor
  __syncthreads();
  for (int e = t; e < EPG; e += 1024) {
    const int sl = esrc[ebase + e] - gbase;
    const int dl = edst[ebase + e] - gbase;
    const unsigned int pos = atomicAdd(&bufB[dl], 1u);
    csr[pos] = (unsigned short)sl;
  }
  __syncthreads();
  const int lane = t & 63, w = t >> 6;            // 16 waves, lane = feature
  const float* __restrict__ zlane = zr + (size_t)gbase * 64 + lane;
  float psum = 0.f;
  for (int nd = w; nd < 512; nd += 16) {
    const unsigned int s = bufA[nd], d = hist[nd];
    float a0 = 0.f, a1 = 0.f, a2 = 0.f, a3 = 0.f;
    unsigned int j = 0;
    for (; j + 4 <= d; j += 4) {                  // 4 independent loads in flight
      const int i0 = csr[s+j], i1 = csr[s+j+1], i2 = csr[s+j+2], i3 = csr[s+j+3];
      const float v0 = zlane[(size_t)i0 * 64];
      const float v1 = zlane[(size_t)i1 * 64];
      const float v2 = zlane[(size_t)i2 * 64];
      const float v3 = zlane[(size_t)i3 * 64];
      a0 += v0; a1 += v1; a2 += v2; a3 += v3;
    }
    for (; j < d; ++j) a0 += zlane[(size_t)csr[s+j] * 64];
    const float acc = (a0 + a1) + (a2 + a3);
    float v = acc / (float)(d > 0 ? d : 1) + xlb[(size_t)(gbase + nd)*64 + lane];
    v = fmaxf(v, 0.f);
    xout[(size_t)(gbase + nd)*64 + lane] = v;
    psum += v;
  }
  red[w][lane] = psum;
  __syncthreads();
  if (t < 64) {
    float s = 0.f;
    #pragma unroll
    for (int ww = 0; ww < 16; ++ww) s += red[ww][t];
    g_xs[g*384 + xs_off + t] = s * (1.f/512.f);
  }
}

// ============================================================================
// Small (n=57 or 7) aggregation over compacted edges + fused gmp.
// ============================================================================
template<int NPER>
__global__ __launch_bounds__(256)
void agg_small(int zr_idx, int xl_idx, int stage, int out_idx, int xs_off)
{
  __shared__ unsigned int hist[NPER], sstart[NPER], scur[NPER];
  __shared__ unsigned short csr[EPG];
  __shared__ float red[4][64];
  const float* __restrict__ zr  = g_feat[zr_idx];
  const float* __restrict__ xlb = g_feat[xl_idx];
  float* __restrict__ xout = g_feat[out_idx];
  const int* __restrict__ esrc = g_esrc[stage];
  const int* __restrict__ edst = g_edst[stage];
  const int g = blockIdx.x, t = threadIdx.x;
  const int gbase = g * NPER, ebase = g * EPG;
  const int m = g_ecnt[stage][g];
  if (t < NPER) hist[t] = 0;
  __syncthreads();
  for (int e = t; e < m; e += 256)
    atomicAdd(&hist[edst[ebase + e] - gbase], 1u);
  __syncthreads();
  if (t == 0) {
    unsigned int run = 0;
    for (int i = 0; i < NPER; ++i) { sstart[i] = run; scur[i] = run; run += hist[i]; }
  }
  __syncthreads();
  for (int e = t; e < m; e += 256) {
    const int sl = esrc[ebase + e] - gbase;
    const int dl = edst[ebase + e] - gbase;
    const unsigned int pos = atomicAdd(&scur[dl], 1u);
    csr[pos] = (unsigned short)sl;
  }
  __syncthreads();
  const int lane = t & 63, w = t >> 6;            // 4 waves
  const float* __restrict__ zlane = zr + (size_t)gbase * 64 + lane;
  float psum = 0.f;
  for (int nd = w; nd < NPER; nd += 4) {
    const unsigned int s = sstart[nd], d = hist[nd];
    float a0 = 0.f, a1 = 0.f, a2 = 0.f, a3 = 0.f;
    unsigned int j = 0;
    for (; j + 4 <= d; j += 4) {
      const int i0 = csr[s+j], i1 = csr[s+j+1], i2 = csr[s+j+2], i3 = csr[s+j+3];
      const float v0 = zlane[(size_t)i0 * 64];
      const float v1 = zlane[(size_t)i1 * 64];
      const float v2 = zlane[(size_t)i2 * 64];
      const float v3 = zlane[(size_t)i3 * 64];
      a0 += v0; a1 += v1; a2 += v2; a3 += v3;
    }
    for (; j < d; ++j) a0 += zlane[(size_t)csr[s+j] * 64];
    const float acc = (a0 + a1) + (a2 + a3);
    float v = acc / (float)(d > 0 ? d : 1) + xlb[(size_t)(gbase + nd)*64 + lane];
    v = fmaxf(v, 0.f);
    xout[(size_t)(gbase + nd)*64 + lane] = v;
    psum += v;
  }
  red[w][lane] = psum;
  __syncthreads();
  if (t < 64) {
    float s = red[0][t] + red[1][t] + red[2][t] + red[3][t];
    g_xs[g*384 + xs_off + t] = s * (1.f/(float)NPER);
  }
}

// ============================================================================
// SAG pool: score (scalar gconv via linearity) -> per-graph top-k (bitonic on
// packed (ordered-float, ~idx) keys == jax.lax.top_k semantics) ->
// new_x = x[perm]*tanh(score[perm]) -> edge compaction with remapped ids.
// ============================================================================
template<int NPER, int NPOW2, int KSEL>
__global__ __launch_bounds__(512)
void sag_pool(int in_idx,
              const int* __restrict__ esrc_ext, const int* __restrict__ edst_ext,
              int in_stage,
              const float* __restrict__ wr, const float* __restrict__ wl,
              const float* __restrict__ pb,
              int xnew_idx, int out_stage)
{
  __shared__ float zs[NPER], swl[NPER], sagg[NPER], sdeg[NPER], sscore[NPER];
  __shared__ unsigned long long keys[NPOW2];
  __shared__ short newpos[NPER];
  __shared__ int scnt;
  const float* __restrict__ xin = g_feat[in_idx];
  float* __restrict__ xnew = g_feat[xnew_idx];
  const int* __restrict__ esrc = (in_stage < 0) ? esrc_ext : g_esrc[in_stage];
  const int* __restrict__ edst = (in_stage < 0) ? edst_ext : g_edst[in_stage];
  int* __restrict__ eosrc = g_esrc[out_stage];
  int* __restrict__ eodst = g_edst[out_stage];
  const int g = blockIdx.x, t = threadIdx.x;
  const int gbase = g * NPER, ebase = g * EPG;
  const int m = (in_stage < 0) ? EPG : g_ecnt[in_stage][g];
  const int lane = t & 63, w = t >> 6;            // 8 waves
  const float wrv = wr[lane], wlv = wl[lane];
  for (int nd = w; nd < NPER; nd += 8) {          // per-node dots via shfl reduce
    const float v = xin[(size_t)(gbase + nd)*64 + lane];
    float a = v * wrv, b = v * wlv;
    #pragma unroll
    for (int off = 32; off > 0; off >>= 1) {
      a += __shfl_xor(a, off);
      b += __shfl_xor(b, off);
    }
    if (lane == 0) { zs[nd] = a; swl[nd] = b; }
  }
  if (t < NPER) { sagg[t] = 0.f; sdeg[t] = 0.f; }
  if (t == 0) scnt = 0;
  __syncthreads();
  for (int e = t; e < m; e += 512) {              // scalar message aggregation
    const int sl = esrc[ebase + e] - gbase;
    const int dl = edst[ebase + e] - gbase;
    atomicAdd(&sagg[dl], zs[sl]);
    atomicAdd(&sdeg[dl], 1.f);
  }
  __syncthreads();
  if (t < NPER)
    sscore[t] = sagg[t] / fmaxf(sdeg[t], 1.f) + pb[0] + swl[t];
  __syncthreads();
  if (t < NPOW2) {                                // pack sort keys
    unsigned long long key = 0ull;
    if (t < NPER) {
      unsigned int u = __float_as_uint(sscore[t]);
      u = (u & 0x80000000u) ? ~u : (u | 0x80000000u);   // order-preserving map
      key = ((unsigned long long)u << 32) | (unsigned int)(~(unsigned int)t);
    }
    keys[t] = key;
  }
  __syncthreads();
  for (int kk = 2; kk <= NPOW2; kk <<= 1) {       // bitonic sort, descending
    for (int j = kk >> 1; j > 0; j >>= 1) {
      if (t < NPOW2) {
        const int ixj = t ^ j;
        if (ixj > t) {
          const unsigned long long a = keys[t], bk = keys[ixj];
          const bool up = ((t & kk) == 0);
          if (up ? (a < bk) : (a > bk)) { keys[t] = bk; keys[ixj] = a; }
        }
      }
      __syncthreads();
    }
  }
  if (t < NPER) newpos[t] = -1;
  __syncthreads();
  if (t < KSEL)
    newpos[(int)(~(unsigned int)(keys[t] & 0xffffffffull))] = (short)t;
  __syncthreads();
  for (int r = w; r < KSEL; r += 8) {             // gather selected nodes
    const int old = (int)(~(unsigned int)(keys[r] & 0xffffffffull));
    const float sc = tanhf(sscore[old]);
    xnew[(size_t)(g*KSEL + r)*64 + lane] =
        xin[(size_t)(gbase + old)*64 + lane] * sc;
  }
  for (int e = t; e < m; e += 512) {              // compact surviving edges
    const int sl = esrc[ebase + e] - gbase;
    const int dl = edst[ebase + e] - gbase;
    const int ns = newpos[sl], nd2 = newpos[dl];
    if (ns >= 0 && nd2 >= 0) {
      const int slot = atomicAdd(&scnt, 1);
      eosrc[ebase + slot] = g*KSEL + ns;
      eodst[ebase + slot] = g*KSEL + nd2;
    }
  }
  __syncthreads();
  if (t == 0) g_ecnt[out_stage][g] = scnt;
}

// ============================================================================
// MLP head: h=[B,384] -> relu(h@W1+b1) -> @W2+b2 -> log_softmax
// ============================================================================
__global__ __launch_bounds__(64)
void head(const float* __restrict__ W1, const float* __restrict__ b1,
          const float* __restrict__ W2, const float* __restrict__ b2,
          float* __restrict__ out)
{
  __shared__ float h[384], o1[64], lg[2];
  const int g = blockIdx.x, t = threadIdx.x;
  for (int i = t; i < 384; i += 64) h[i] = g_xs[g*384 + i];
  __syncthreads();
  float acc = b1[t];
  for (int j = 0; j < 384; ++j) acc += h[j] * W1[j*64 + t];
  o1[t] = fmaxf(acc, 0.f);
  __syncthreads();
  if (t < 2) {
    float a2 = b2[t];
    for (int f2 = 0; f2 < 64; ++f2) a2 += o1[f2] * W2[f2*2 + t];
    lg[t] = a2;
  }
  __syncthreads();
  if (t < 2) {
    const float mx = fmaxf(lg[0], lg[1]);
    const float lse = mx + logf(expf(lg[0]-mx) + expf(lg[1]-mx));
    out[g*2 + t] = lg[t] - lse;
  }
}

// ============================================================================
extern "C" void kernel_launch(void* const* d_in, const int* in_sizes, int n_in,
                              void* d_out, int out_size, void* d_ws, size_t ws_size,
                              hipStream_t stream)
{
  (void)in_sizes; (void)n_in; (void)d_ws; (void)ws_size; (void)out_size;
  const float* x    = (const float*)d_in[0];
  const int*   ei   = (const int*)d_in[1];
  const float* c1Wr = (const float*)d_in[2];
  const float* c1Wl = (const float*)d_in[3];
  const float* c1b  = (const float*)d_in[4];
  const float* cWr  = (const float*)d_in[5];
  const float* cWl  = (const float*)d_in[6];
  const float* cb   = (const float*)d_in[7];
  const float* pWr  = (const float*)d_in[8];
  const float* pWl  = (const float*)d_in[9];
  const float* pb   = (const float*)d_in[10];
  const float* l1W  = (const float*)d_in[11];
  const float* l1b  = (const float*)d_in[12];
  const float* l2W  = (const float*)d_in[13];
  const float* l2b  = (const float*)d_in[14];
  float* out = (float*)d_out;
  const int* esrc = ei;
  const int* edst = ei + ETOT;

  // conv1 (160->64) + relu, xs[0]
  mm_dual<160><<<NN0/64, 256, 0, stream>>>(x, -1, c1Wr, c1Wl, c1b, 0, 1);
  agg_full<<<NB, 1024, 0, stream>>>(0, 1, esrc, edst, 1, 0);
  // convs[0] + relu, xs[1]
  mm_dual<64><<<NN0/64, 256, 0, stream>>>(nullptr, 1, cWr, cWl, cb, 0, 2);
  agg_full<<<NB, 1024, 0, stream>>>(0, 2, esrc, edst, 2, 64);
  // pool0: 512 -> 57
  sag_pool<512,512,57><<<NB, 512, 0, stream>>>(2, esrc, edst, -1, pWr, pWl, pb, 0, 0);
  // convs[1] + relu, xs[2]   (14592 rows = 228*64)
  mm_dual<64><<<228, 256, 0, stream>>>(nullptr, 0, cWr+4096, cWl+4096, cb+64, 1, 2);
  agg_small<57><<<NB, 256, 0, stream>>>(1, 2, 0, 2, 128);
  // convs[2] + relu, xs[3]
  mm_dual<64><<<228, 256, 0, stream>>>(nullptr, 2, cWr+8192, cWl+8192, cb+128, 1, 0);
  agg_small<57><<<NB, 256, 0, stream>>>(1, 0, 0, 0, 192);
  // pool1: 57 -> 7
  sag_pool<57,64,7><<<NB, 512, 0, stream>>>(0, nullptr, nullptr, 0, pWr+64, pWl+64, pb+1, 1, 1);
  // convs[3] + relu, xs[4]   (1792 rows = 28*64)
  mm_dual<64><<<28, 256, 0, stream>>>(nullptr, 1, cWr+12288, cWl+12288, cb+192, 0, 2);
  agg_small<7><<<NB, 256, 0, stream>>>(0, 2, 1, 2, 256);
  // convs[4] + relu, xs[5]
  mm_dual<64><<<28, 256, 0, stream>>>(nullptr, 2, cWr+16384, cWl+16384, cb+256, 0, 1);
  agg_small<7><<<NB, 256, 0, stream>>>(0, 1, 1, 1, 320);
  // head
  head<<<NB, 64, 0, stream>>>(l1W, l1b, l2W, l2b, out);
}

// Round 11
// 495.413 us; speedup vs baseline: 1.0636x; 1.0636x over previous
//
#include <hip/hip_runtime.h>
#include <math.h>

namespace {
constexpr int NB   = 256;          // graphs
constexpr int EPG  = 8192;         // edges per graph
constexpr int ETOT = NB * EPG;     // 2,097,152
constexpr int FH   = 64;           // hidden dim
constexpr int NN0  = NB * 512;     // 131072 nodes at full size
}

// ---- scratch (device globals: write-before-read each call, deterministic) ----
__device__ float g_feat[3][(size_t)NN0 * FH];   // rotating node-feature buffers
__device__ float g_xs[NB * 6 * FH];             // jumping-knowledge concat
__device__ int   g_esrc[2][ETOT];               // compacted edges (stage 0/1)
__device__ int   g_edst[2][ETOT];
__device__ int   g_ecnt[2][NB];

// ============================================================================
// Dual matmul: zr = x@Wr ; xl = x@Wl + b   (x: [M,K], W: [K,64], M % 64 == 0)
// v5 (plateau at ~117us for K=160; kept as-is).
// ============================================================================
template<int K>
__global__ __launch_bounds__(256)
void mm_dual(const float* __restrict__ xext, int in_idx,
             const float* __restrict__ Wr, const float* __restrict__ Wl,
             const float* __restrict__ bias, int zr_idx, int xl_idx)
{
  constexpr int RPB = 64;           // rows per block
  constexpr int KC  = 32;           // k-chunk staged in LDS
  __shared__ float xs[RPB][KC];     // 8 KB
  __shared__ float wrT[KC/4][64][4];// 8 KB
  __shared__ float wlT[KC/4][64][4];// 8 KB
  const float* __restrict__ x = (in_idx < 0) ? xext : g_feat[in_idx];
  float* __restrict__ zr = g_feat[zr_idx];
  float* __restrict__ xl = g_feat[xl_idx];
  const int t = threadIdx.x;
  const int rowbase = blockIdx.x * RPB;
  const int f  = t & 31;
  const int rg = t >> 5;
  const int wv = t >> 6;
  const int wc = t & 63;
  const int wq = t >> 6;
  float ar0[8], ar1[8], al0[8], al1[8];
  #pragma unroll
  for (int r = 0; r < 8; ++r) { ar0[r]=0.f; ar1[r]=0.f; al0[r]=0.f; al1[r]=0.f; }

  for (int c = 0; c < K / KC; ++c) {
    __syncthreads();
    #pragma unroll
    for (int i = 0; i < 2; ++i) {
      const int idx = t + i * 256;
      const int r = idx >> 3, q = idx & 7;
      const float* gp = &x[(size_t)(rowbase + r) * K + c * KC + q * 4];
      float* lp = &xs[0][0] + (size_t)(i * 256 + wv * 64) * 4;
      __builtin_amdgcn_global_load_lds(
          (const __attribute__((address_space(1))) unsigned int*)gp,
          (__attribute__((address_space(3))) unsigned int*)lp, 16, 0, 0);
    }
    #pragma unroll
    for (int h = 0; h < 2; ++h) {
      const int kq = wq * 2 + h;
      #pragma unroll
      for (int i = 0; i < 4; ++i) {
        const int krow = c * KC + kq * 4 + i;
        wrT[kq][wc][i] = Wr[(size_t)krow * 64 + wc];
        wlT[kq][wc][i] = Wl[(size_t)krow * 64 + wc];
      }
    }
    __syncthreads();
    for (int k4 = 0; k4 < KC / 4; ++k4) {
      const float4 wr0 = *reinterpret_cast<const float4*>(&wrT[k4][f][0]);
      const float4 wr1 = *reinterpret_cast<const float4*>(&wrT[k4][f+32][0]);
      const float4 wl0 = *reinterpret_cast<const float4*>(&wlT[k4][f][0]);
      const float4 wl1 = *reinterpret_cast<const float4*>(&wlT[k4][f+32][0]);
      #pragma unroll
      for (int r = 0; r < 8; ++r) {
        const float4 xv = *reinterpret_cast<const float4*>(&xs[rg*8 + r][k4*4]);
        ar0[r] += xv.x*wr0.x + xv.y*wr0.y + xv.z*wr0.z + xv.w*wr0.w;
        ar1[r] += xv.x*wr1.x + xv.y*wr1.y + xv.z*wr1.z + xv.w*wr1.w;
        al0[r] += xv.x*wl0.x + xv.y*wl0.y + xv.z*wl0.z + xv.w*wl0.w;
        al1[r] += xv.x*wl1.x + xv.y*wl1.y + xv.z*wl1.z + xv.w*wl1.w;
      }
    }
  }
  const float bv0 = bias[f], bv1 = bias[f + 32];
  #pragma unroll
  for (int r = 0; r < 8; ++r) {
    const size_t row = (size_t)(rowbase + rg * 8 + r);
    zr[row * 64 + f]      = ar0[r];
    zr[row * 64 + f + 32] = ar1[r];
    xl[row * 64 + f]      = al0[r] + bv0;
    xl[row * 64 + f + 32] = al1[r] + bv1;
  }
}

// ============================================================================
// Full-size (n=512/graph) mean-aggregation + residual + relu + fused gmp.
// ============================================================================
__global__ __launch_bounds__(1024)
void agg_full(int zr_idx, int xl_idx,
              const int* __restrict__ esrc, const int* __restrict__ edst,
              int out_idx, int xs_off)
{
  __shared__ unsigned int hist[512], bufA[512], bufB[512];
  __shared__ unsigned short csr[EPG];
  __shared__ float red[16][64];
  const float* __restrict__ zr  = g_feat[zr_idx];
  const float* __restrict__ xlb = g_feat[xl_idx];
  float* __restrict__ xout = g_feat[out_idx];
  const int g = blockIdx.x, t = threadIdx.x;
  const int gbase = g * 512, ebase = g * EPG;
  for (int i = t; i < 512; i += 1024) hist[i] = 0;
  __syncthreads();
  for (int e = t; e < EPG; e += 1024)
    atomicAdd(&hist[edst[ebase + e] - gbase], 1u);
  __syncthreads();
  if (t < 512) bufA[t] = hist[t];
  __syncthreads();
  unsigned int *pa = bufA, *pb = bufB;
  for (int off = 1; off < 512; off <<= 1) {
    if (t < 512) {
      unsigned int v = pa[t];
      if (t >= off) v += pa[t - off];
      pb[t] = v;
    }
    __syncthreads();
    unsigned int* tmp = pa; pa = pb; pb = tmp;
  }
  unsigned int excl = 0;
  if (t < 512) excl = pa[t] - hist[t];
  __syncthreads();
  if (t < 512) { bufA[t] = excl; bufB[t] = excl; }
  __syncthreads();
  for (int e = t; e < EPG; e += 1024) {
    const int sl = esrc[ebase + e] - gbase;
    const int dl = edst[ebase + e] - gbase;
    const unsigned int pos = atomicAdd(&bufB[dl], 1u);
    csr[pos] = (unsigned short)sl;
  }
  __syncthreads();
  const int lane = t & 63, w = t >> 6;
  const float* __restrict__ zlane = zr + (size_t)gbase * 64 + lane;
  float psum = 0.f;
  for (int nd = w; nd < 512; nd += 16) {
    const unsigned int s = bufA[nd], d = hist[nd];
    float a0 = 0.f, a1 = 0.f, a2 = 0.f, a3 = 0.f;
    unsigned int j = 0;
    for (; j + 4 <= d; j += 4) {
      const int i0 = csr[s+j], i1 = csr[s+j+1], i2 = csr[s+j+2], i3 = csr[s+j+3];
      const float v0 = zlane[(size_t)i0 * 64];
      const float v1 = zlane[(size_t)i1 * 64];
      const float v2 = zlane[(size_t)i2 * 64];
      const float v3 = zlane[(size_t)i3 * 64];
      a0 += v0; a1 += v1; a2 += v2; a3 += v3;
    }
    for (; j < d; ++j) a0 += zlane[(size_t)csr[s+j] * 64];
    const float acc = (a0 + a1) + (a2 + a3);
    float v = acc / (float)(d > 0 ? d : 1) + xlb[(size_t)(gbase + nd)*64 + lane];
    v = fmaxf(v, 0.f);
    xout[(size_t)(gbase + nd)*64 + lane] = v;
    psum += v;
  }
  red[w][lane] = psum;
  __syncthreads();
  if (t < 64) {
    float s = 0.f;
    #pragma unroll
    for (int ww = 0; ww < 16; ++ww) s += red[ww][t];
    g_xs[g*384 + xs_off + t] = s * (1.f/512.f);
  }
}

// ============================================================================
// SAG pool 0 (512 -> 57), unchanged.
// ============================================================================
template<int NPER, int NPOW2, int KSEL>
__global__ __launch_bounds__(512)
void sag_pool(int in_idx,
              const int* __restrict__ esrc_ext, const int* __restrict__ edst_ext,
              int in_stage,
              const float* __restrict__ wr, const float* __restrict__ wl,
              const float* __restrict__ pb,
              int xnew_idx, int out_stage)
{
  __shared__ float zs[NPER], swl[NPER], sagg[NPER], sdeg[NPER], sscore[NPER];
  __shared__ unsigned long long keys[NPOW2];
  __shared__ short newpos[NPER];
  __shared__ int scnt;
  const float* __restrict__ xin = g_feat[in_idx];
  float* __restrict__ xnew = g_feat[xnew_idx];
  const int* __restrict__ esrc = (in_stage < 0) ? esrc_ext : g_esrc[in_stage];
  const int* __restrict__ edst = (in_stage < 0) ? edst_ext : g_edst[in_stage];
  int* __restrict__ eosrc = g_esrc[out_stage];
  int* __restrict__ eodst = g_edst[out_stage];
  const int g = blockIdx.x, t = threadIdx.x;
  const int gbase = g * NPER, ebase = g * EPG;
  const int m = (in_stage < 0) ? EPG : g_ecnt[in_stage][g];
  const int lane = t & 63, w = t >> 6;
  const float wrv = wr[lane], wlv = wl[lane];
  for (int nd = w; nd < NPER; nd += 8) {
    const float v = xin[(size_t)(gbase + nd)*64 + lane];
    float a = v * wrv, b = v * wlv;
    #pragma unroll
    for (int off = 32; off > 0; off >>= 1) {
      a += __shfl_xor(a, off);
      b += __shfl_xor(b, off);
    }
    if (lane == 0) { zs[nd] = a; swl[nd] = b; }
  }
  if (t < NPER) { sagg[t] = 0.f; sdeg[t] = 0.f; }
  if (t == 0) scnt = 0;
  __syncthreads();
  for (int e = t; e < m; e += 512) {
    const int sl = esrc[ebase + e] - gbase;
    const int dl = edst[ebase + e] - gbase;
    atomicAdd(&sagg[dl], zs[sl]);
    atomicAdd(&sdeg[dl], 1.f);
  }
  __syncthreads();
  if (t < NPER)
    sscore[t] = sagg[t] / fmaxf(sdeg[t], 1.f) + pb[0] + swl[t];
  __syncthreads();
  if (t < NPOW2) {
    unsigned long long key = 0ull;
    if (t < NPER) {
      unsigned int u = __float_as_uint(sscore[t]);
      u = (u & 0x80000000u) ? ~u : (u | 0x80000000u);
      key = ((unsigned long long)u << 32) | (unsigned int)(~(unsigned int)t);
    }
    keys[t] = key;
  }
  __syncthreads();
  for (int kk = 2; kk <= NPOW2; kk <<= 1) {
    for (int j = kk >> 1; j > 0; j >>= 1) {
      if (t < NPOW2) {
        const int ixj = t ^ j;
        if (ixj > t) {
          const unsigned long long a = keys[t], bk = keys[ixj];
          const bool up = ((t & kk) == 0);
          if (up ? (a < bk) : (a > bk)) { keys[t] = bk; keys[ixj] = a; }
        }
      }
      __syncthreads();
    }
  }
  if (t < NPER) newpos[t] = -1;
  __syncthreads();
  if (t < KSEL)
    newpos[(int)(~(unsigned int)(keys[t] & 0xffffffffull))] = (short)t;
  __syncthreads();
  for (int r = w; r < KSEL; r += 8) {
    const int old = (int)(~(unsigned int)(keys[r] & 0xffffffffull));
    const float sc = tanhf(sscore[old]);
    xnew[(size_t)(g*KSEL + r)*64 + lane] =
        xin[(size_t)(gbase + old)*64 + lane] * sc;
  }
  for (int e = t; e < m; e += 512) {
    const int sl = esrc[ebase + e] - gbase;
    const int dl = edst[ebase + e] - gbase;
    const int ns = newpos[sl], nd2 = newpos[dl];
    if (ns >= 0 && nd2 >= 0) {
      const int slot = atomicAdd(&scnt, 1);
      eosrc[ebase + slot] = g*KSEL + ns;
      eodst[ebase + slot] = g*KSEL + nd2;
    }
  }
  __syncthreads();
  if (t == 0) g_ecnt[out_stage][g] = scnt;
}

// ============================================================================
// Fused tail: per graph, everything after pool0 (convs[1..4], pool1, gmp's).
// 1 block/graph, 512 threads, ~54 KB static LDS. Replaces 9 launches.
// ============================================================================
__device__ __forceinline__ void conv_small(
    float* X, float* Z, float* ACC, float* w_s, const float* deg,
    const float* Wr, const float* Wl, const float* bias,
    int n, const int* esrc, const int* edst, int m, int gb, int ebase,
    int xs_off, int g, int t, int lane, int w)
{
  // step 1: Z = X @ Wr
  for (int i = t; i < n*64; i += 512) { Z[i] = 0.f; ACC[i] = 0.f; }
  __syncthreads();
  for (int kc = 0; kc < 4; ++kc) {
    for (int i = t; i < 1024; i += 512) w_s[i] = Wr[kc*1024 + i];
    __syncthreads();
    for (int r = w; r < n; r += 8) {
      float zacc = 0.f;
      #pragma unroll
      for (int k = 0; k < 16; ++k)
        zacc += X[r*64 + kc*16 + k] * w_s[k*64 + lane];
      Z[r*64 + lane] += zacc;
    }
    __syncthreads();
  }
  // step 2: ACC[dst] += Z[src] over edges
  for (int e = w; e < m; e += 8) {
    const int sl = esrc[ebase + e] - gb;
    const int dl = edst[ebase + e] - gb;
    atomicAdd(&ACC[dl*64 + lane], Z[sl*64 + lane]);
  }
  __syncthreads();
  // step 3a: Z = ACC/deg + b
  for (int i = t; i < n*64; i += 512) {
    const int r = i >> 6, f = i & 63;
    Z[i] = ACC[i] / fmaxf(deg[r], 1.f) + bias[f];
  }
  __syncthreads();
  // step 3b: Z += X @ Wl
  for (int kc = 0; kc < 4; ++kc) {
    for (int i = t; i < 1024; i += 512) w_s[i] = Wl[kc*1024 + i];
    __syncthreads();
    for (int r = w; r < n; r += 8) {
      float zacc = 0.f;
      #pragma unroll
      for (int k = 0; k < 16; ++k)
        zacc += X[r*64 + kc*16 + k] * w_s[k*64 + lane];
      Z[r*64 + lane] += zacc;
    }
    __syncthreads();
  }
  // step 3c: X = relu(Z) ; gmp
  for (int i = t; i < n*64; i += 512) X[i] = fmaxf(Z[i], 0.f);
  __syncthreads();
  if (t < 64) {
    float s = 0.f;
    for (int r = 0; r < n; ++r) s += X[r*64 + t];
    g_xs[g*384 + xs_off + t] = s / (float)n;
  }
  __syncthreads();
}

__global__ __launch_bounds__(512)
void tail(const float* __restrict__ cWr, const float* __restrict__ cWl,
          const float* __restrict__ cb,
          const float* __restrict__ pWr, const float* __restrict__ pWl,
          const float* __restrict__ pb)
{
  __shared__ float X[57*64], Z[57*64], ACC[57*64];   // 42.75 KB
  __shared__ float w_s[16*64];                       // 4 KB
  __shared__ float deg[64];
  __shared__ float zs[64], swl[64], sagg[64], sscore[64];
  __shared__ unsigned long long keys[64];
  __shared__ short newpos[64];
  __shared__ int scnt;
  const int g = blockIdx.x, t = threadIdx.x;
  const int lane = t & 63, w = t >> 6;               // 8 waves
  const int ebase = g * EPG;

  // load pool0 output
  for (int i = t; i < 57*64; i += 512) X[i] = g_feat[0][(size_t)(g*57)*64 + i];
  // deg for stage-0 edges
  const int m0 = g_ecnt[0][g];
  if (t < 64) deg[t] = 0.f;
  __syncthreads();
  for (int e = t; e < m0; e += 512)
    atomicAdd(&deg[g_edst[0][ebase + e] - g*57], 1.f);
  __syncthreads();

  // convs[1], convs[2]  (n=57, stage-0 edges)
  conv_small(X, Z, ACC, w_s, deg, cWr + 4096,  cWl + 4096,  cb + 64,
             57, g_esrc[0], g_edst[0], m0, g*57, ebase, 128, g, t, lane, w);
  conv_small(X, Z, ACC, w_s, deg, cWr + 8192,  cWl + 8192,  cb + 128,
             57, g_esrc[0], g_edst[0], m0, g*57, ebase, 192, g, t, lane, w);

  // ---- pool1: 57 -> 7 ----
  {
    const float pwrv = pWr[64 + lane], pwlv = pWl[64 + lane];
    for (int r = w; r < 57; r += 8) {
      float a = X[r*64 + lane] * pwrv, b = X[r*64 + lane] * pwlv;
      #pragma unroll
      for (int off = 32; off > 0; off >>= 1) {
        a += __shfl_xor(a, off);
        b += __shfl_xor(b, off);
      }
      if (lane == 0) { zs[r] = a; swl[r] = b; }
    }
    if (t < 64) sagg[t] = 0.f;
    if (t == 0) scnt = 0;
    __syncthreads();
    for (int e = t; e < m0; e += 512)
      atomicAdd(&sagg[g_edst[0][ebase + e] - g*57],
                zs[g_esrc[0][ebase + e] - g*57]);
    __syncthreads();
    if (t < 57) sscore[t] = sagg[t] / fmaxf(deg[t], 1.f) + pb[1] + swl[t];
    __syncthreads();
    if (t < 64) {
      unsigned long long key = 0ull;
      if (t < 57) {
        unsigned int u = __float_as_uint(sscore[t]);
        u = (u & 0x80000000u) ? ~u : (u | 0x80000000u);
        key = ((unsigned long long)u << 32) | (unsigned int)(~(unsigned int)t);
      }
      keys[t] = key;
    }
    __syncthreads();
    for (int kk = 2; kk <= 64; kk <<= 1) {
      for (int j = kk >> 1; j > 0; j >>= 1) {
        if (t < 64) {
          const int ixj = t ^ j;
          if (ixj > t) {
            const unsigned long long a = keys[t], bk = keys[ixj];
            const bool up = ((t & kk) == 0);
            if (up ? (a < bk) : (a > bk)) { keys[t] = bk; keys[ixj] = a; }
          }
        }
        __syncthreads();
      }
    }
    if (t < 64) newpos[t] = -1;
    __syncthreads();
    if (t < 7)
      newpos[(int)(~(unsigned int)(keys[t] & 0xffffffffull))] = (short)t;
    __syncthreads();
    for (int r = w; r < 7; r += 8) {           // gather into Z (X still live)
      const int old = (int)(~(unsigned int)(keys[r] & 0xffffffffull));
      const float sc = tanhf(sscore[old]);
      Z[r*64 + lane] = X[old*64 + lane] * sc;
    }
    // compact surviving edges to stage 1 (global ids g*7+*)
    for (int e = t; e < m0; e += 512) {
      const int sl = g_esrc[0][ebase + e] - g*57;
      const int dl = g_edst[0][ebase + e] - g*57;
      const int ns = newpos[sl], nd2 = newpos[dl];
      if (ns >= 0 && nd2 >= 0) {
        const int slot = atomicAdd(&scnt, 1);
        g_esrc[1][ebase + slot] = g*7 + ns;
        g_edst[1][ebase + slot] = g*7 + nd2;
      }
    }
    __syncthreads();
    for (int i = t; i < 7*64; i += 512) X[i] = Z[i];
    if (t < 64) deg[t] = 0.f;
    __syncthreads();
  }
  const int m1 = scnt;
  for (int e = t; e < m1; e += 512)
    atomicAdd(&deg[g_edst[1][ebase + e] - g*7], 1.f);
  __syncthreads();

  // convs[3], convs[4]  (n=7, stage-1 edges)
  conv_small(X, Z, ACC, w_s, deg, cWr + 12288, cWl + 12288, cb + 192,
             7, g_esrc[1], g_edst[1], m1, g*7, ebase, 256, g, t, lane, w);
  conv_small(X, Z, ACC, w_s, deg, cWr + 16384, cWl + 16384, cb + 256,
             7, g_esrc[1], g_edst[1], m1, g*7, ebase, 320, g, t, lane, w);
}

// ============================================================================
// MLP head: h=[B,384] -> relu(h@W1+b1) -> @W2+b2 -> log_softmax
// ============================================================================
__global__ __launch_bounds__(64)
void head(const float* __restrict__ W1, const float* __restrict__ b1,
          const float* __restrict__ W2, const float* __restrict__ b2,
          float* __restrict__ out)
{
  __shared__ float h[384], o1[64], lg[2];
  const int g = blockIdx.x, t = threadIdx.x;
  for (int i = t; i < 384; i += 64) h[i] = g_xs[g*384 + i];
  __syncthreads();
  float acc = b1[t];
  for (int j = 0; j < 384; ++j) acc += h[j] * W1[j*64 + t];
  o1[t] = fmaxf(acc, 0.f);
  __syncthreads();
  if (t < 2) {
    float a2 = b2[t];
    for (int f2 = 0; f2 < 64; ++f2) a2 += o1[f2] * W2[f2*2 + t];
    lg[t] = a2;
  }
  __syncthreads();
  if (t < 2) {
    const float mx = fmaxf(lg[0], lg[1]);
    const float lse = mx + logf(expf(lg[0]-mx) + expf(lg[1]-mx));
    out[g*2 + t] = lg[t] - lse;
  }
}

// ============================================================================
extern "C" void kernel_launch(void* const* d_in, const int* in_sizes, int n_in,
                              void* d_out, int out_size, void* d_ws, size_t ws_size,
                              hipStream_t stream)
{
  (void)in_sizes; (void)n_in; (void)d_ws; (void)ws_size; (void)out_size;
  const float* x    = (const float*)d_in[0];
  const int*   ei   = (const int*)d_in[1];
  const float* c1Wr = (const float*)d_in[2];
  const float* c1Wl = (const float*)d_in[3];
  const float* c1b  = (const float*)d_in[4];
  const float* cWr  = (const float*)d_in[5];
  const float* cWl  = (const float*)d_in[6];
  const float* cb   = (const float*)d_in[7];
  const float* pWr  = (const float*)d_in[8];
  const float* pWl  = (const float*)d_in[9];
  const float* pb   = (const float*)d_in[10];
  const float* l1W  = (const float*)d_in[11];
  const float* l1b  = (const float*)d_in[12];
  const float* l2W  = (const float*)d_in[13];
  const float* l2b  = (const float*)d_in[14];
  float* out = (float*)d_out;
  const int* esrc = ei;
  const int* edst = ei + ETOT;

  // conv1 (160->64) + relu, xs[0]
  mm_dual<160><<<NN0/64, 256, 0, stream>>>(x, -1, c1Wr, c1Wl, c1b, 0, 1);
  agg_full<<<NB, 1024, 0, stream>>>(0, 1, esrc, edst, 1, 0);
  // convs[0] + relu, xs[1]
  mm_dual<64><<<NN0/64, 256, 0, stream>>>(nullptr, 1, cWr, cWl, cb, 0, 2);
  agg_full<<<NB, 1024, 0, stream>>>(0, 2, esrc, edst, 2, 64);
  // pool0: 512 -> 57
  sag_pool<512,512,57><<<NB, 512, 0, stream>>>(2, esrc, edst, -1, pWr, pWl, pb, 0, 0);
  // fused tail: convs[1..4] + pool1 + gmp's
  tail<<<NB, 512, 0, stream>>>(cWr, cWl, cb, pWr, pWl, pb);
  // head
  head<<<NB, 64, 0, stream>>>(l1W, l1b, l2W, l2b, out);
}

// Round 12
// 409.747 us; speedup vs baseline: 1.2860x; 1.2091x over previous
//
#include <hip/hip_runtime.h>
#include <math.h>

namespace {
constexpr int NB   = 256;          // graphs
constexpr int EPG  = 8192;         // edges per graph
constexpr int ETOT = NB * EPG;     // 2,097,152
constexpr int FH   = 64;           // hidden dim
constexpr int NN0  = NB * 512;     // 131072 nodes at full size
}

// ---- scratch (device globals: write-before-read each call, deterministic) ----
__device__ float g_feat[3][(size_t)NN0 * FH];   // rotating node-feature buffers
__device__ float g_xs[NB * 6 * FH];             // jumping-knowledge concat
__device__ int   g_esrc[2][ETOT];               // compacted edges (stage 0/1)
__device__ int   g_edst[2][ETOT];
__device__ int   g_ecnt[2][NB];
__device__ unsigned short g_csr[ETOT];          // shared CSR (built once/call)
__device__ unsigned int   g_deg[NN0], g_start[NN0];

// ============================================================================
// Dual matmul: zr = x@Wr ; xl = x@Wl + b
// v6: inner loop as explicit fmaf chains (compiler can't reassociate mul+add
// without fast-math -> was emitting 2x VALU ops; this halves VALU issue).
// ============================================================================
template<int K>
__global__ __launch_bounds__(256)
void mm_dual(const float* __restrict__ xext, int in_idx,
             const float* __restrict__ Wr, const float* __restrict__ Wl,
             const float* __restrict__ bias, int zr_idx, int xl_idx)
{
  constexpr int RPB = 64;           // rows per block
  constexpr int KC  = 32;           // k-chunk staged in LDS
  __shared__ float xs[RPB][KC];     // 8 KB
  __shared__ float wrT[KC/4][64][4];// 8 KB
  __shared__ float wlT[KC/4][64][4];// 8 KB
  const float* __restrict__ x = (in_idx < 0) ? xext : g_feat[in_idx];
  float* __restrict__ zr = g_feat[zr_idx];
  float* __restrict__ xl = g_feat[xl_idx];
  const int t = threadIdx.x;
  const int rowbase = blockIdx.x * RPB;
  const int f  = t & 31;
  const int rg = t >> 5;
  const int wv = t >> 6;
  const int wc = t & 63;
  const int wq = t >> 6;
  float ar0[8], ar1[8], al0[8], al1[8];
  #pragma unroll
  for (int r = 0; r < 8; ++r) { ar0[r]=0.f; ar1[r]=0.f; al0[r]=0.f; al1[r]=0.f; }

  for (int c = 0; c < K / KC; ++c) {
    __syncthreads();
    #pragma unroll
    for (int i = 0; i < 2; ++i) {
      const int idx = t + i * 256;
      const int r = idx >> 3, q = idx & 7;
      const float* gp = &x[(size_t)(rowbase + r) * K + c * KC + q * 4];
      float* lp = &xs[0][0] + (size_t)(i * 256 + wv * 64) * 4;
      __builtin_amdgcn_global_load_lds(
          (const __attribute__((address_space(1))) unsigned int*)gp,
          (__attribute__((address_space(3))) unsigned int*)lp, 16, 0, 0);
    }
    #pragma unroll
    for (int h = 0; h < 2; ++h) {
      const int kq = wq * 2 + h;
      #pragma unroll
      for (int i = 0; i < 4; ++i) {
        const int krow = c * KC + kq * 4 + i;
        wrT[kq][wc][i] = Wr[(size_t)krow * 64 + wc];
        wlT[kq][wc][i] = Wl[(size_t)krow * 64 + wc];
      }
    }
    __syncthreads();
    for (int k4 = 0; k4 < KC / 4; ++k4) {
      const float4 wr0 = *reinterpret_cast<const float4*>(&wrT[k4][f][0]);
      const float4 wr1 = *reinterpret_cast<const float4*>(&wrT[k4][f+32][0]);
      const float4 wl0 = *reinterpret_cast<const float4*>(&wlT[k4][f][0]);
      const float4 wl1 = *reinterpret_cast<const float4*>(&wlT[k4][f+32][0]);
      #pragma unroll
      for (int r = 0; r < 8; ++r) {
        const float4 xv = *reinterpret_cast<const float4*>(&xs[rg*8 + r][k4*4]);
        float a0 = ar0[r], a1 = ar1[r], b0 = al0[r], b1 = al1[r];
        a0 = fmaf(xv.x, wr0.x, a0); a0 = fmaf(xv.y, wr0.y, a0);
        a0 = fmaf(xv.z, wr0.z, a0); a0 = fmaf(xv.w, wr0.w, a0);
        a1 = fmaf(xv.x, wr1.x, a1); a1 = fmaf(xv.y, wr1.y, a1);
        a1 = fmaf(xv.z, wr1.z, a1); a1 = fmaf(xv.w, wr1.w, a1);
        b0 = fmaf(xv.x, wl0.x, b0); b0 = fmaf(xv.y, wl0.y, b0);
        b0 = fmaf(xv.z, wl0.z, b0); b0 = fmaf(xv.w, wl0.w, b0);
        b1 = fmaf(xv.x, wl1.x, b1); b1 = fmaf(xv.y, wl1.y, b1);
        b1 = fmaf(xv.z, wl1.z, b1); b1 = fmaf(xv.w, wl1.w, b1);
        ar0[r] = a0; ar1[r] = a1; al0[r] = b0; al1[r] = b1;
      }
    }
  }
  const float bv0 = bias[f], bv1 = bias[f + 32];
  #pragma unroll
  for (int r = 0; r < 8; ++r) {
    const size_t row = (size_t)(rowbase + rg * 8 + r);
    zr[row * 64 + f]      = ar0[r];
    zr[row * 64 + f + 32] = ar1[r];
    xl[row * 64 + f]      = al0[r] + bv0;
    xl[row * 64 + f + 32] = al1[r] + bv1;
  }
}

// ============================================================================
// agg_full_build: builds CSR in LDS (hist+scan+scatter), SAVES it to global,
// then does mean-agg + residual + relu + gmp.
// ============================================================================
__global__ __launch_bounds__(1024)
void agg_full_build(int zr_idx, int xl_idx,
                    const int* __restrict__ esrc, const int* __restrict__ edst,
                    int out_idx, int xs_off)
{
  __shared__ unsigned int hist[512], bufA[512], bufB[512];
  __shared__ unsigned short csr[EPG];
  __shared__ float red[16][64];
  const float* __restrict__ zr  = g_feat[zr_idx];
  const float* __restrict__ xlb = g_feat[xl_idx];
  float* __restrict__ xout = g_feat[out_idx];
  const int g = blockIdx.x, t = threadIdx.x;
  const int gbase = g * 512, ebase = g * EPG;
  for (int i = t; i < 512; i += 1024) hist[i] = 0;
  __syncthreads();
  for (int e = t; e < EPG; e += 1024)
    atomicAdd(&hist[edst[ebase + e] - gbase], 1u);
  __syncthreads();
  if (t < 512) bufA[t] = hist[t];
  __syncthreads();
  unsigned int *pa = bufA, *pb = bufB;
  for (int off = 1; off < 512; off <<= 1) {
    if (t < 512) {
      unsigned int v = pa[t];
      if (t >= off) v += pa[t - off];
      pb[t] = v;
    }
    __syncthreads();
    unsigned int* tmp = pa; pa = pb; pb = tmp;
  }
  unsigned int excl = 0;
  if (t < 512) excl = pa[t] - hist[t];
  __syncthreads();
  if (t < 512) { bufA[t] = excl; bufB[t] = excl; }
  __syncthreads();
  for (int e = t; e < EPG; e += 1024) {
    const int sl = esrc[ebase + e] - gbase;
    const int dl = edst[ebase + e] - gbase;
    const unsigned int pos = atomicAdd(&bufB[dl], 1u);
    csr[pos] = (unsigned short)sl;
  }
  __syncthreads();
  // persist CSR for downstream kernels
  if (t < 512) { g_deg[gbase + t] = hist[t]; g_start[gbase + t] = bufA[t]; }
  {
    unsigned int* gcsr32 = reinterpret_cast<unsigned int*>(&g_csr[ebase]);
    const unsigned int* lcsr32 = reinterpret_cast<const unsigned int*>(csr);
    for (int i = t; i < EPG/2; i += 1024) gcsr32[i] = lcsr32[i];
  }
  const int lane = t & 63, w = t >> 6;
  const float* __restrict__ zlane = zr + (size_t)gbase * 64 + lane;
  float psum = 0.f;
  for (int nd = w; nd < 512; nd += 16) {
    const unsigned int s = bufA[nd], d = hist[nd];
    float a0 = 0.f, a1 = 0.f, a2 = 0.f, a3 = 0.f;
    unsigned int j = 0;
    for (; j + 4 <= d; j += 4) {
      const int i0 = csr[s+j], i1 = csr[s+j+1], i2 = csr[s+j+2], i3 = csr[s+j+3];
      const float v0 = zlane[(size_t)i0 * 64];
      const float v1 = zlane[(size_t)i1 * 64];
      const float v2 = zlane[(size_t)i2 * 64];
      const float v3 = zlane[(size_t)i3 * 64];
      a0 += v0; a1 += v1; a2 += v2; a3 += v3;
    }
    for (; j < d; ++j) a0 += zlane[(size_t)csr[s+j] * 64];
    const float acc = (a0 + a1) + (a2 + a3);
    float v = acc / (float)(d > 0 ? d : 1) + xlb[(size_t)(gbase + nd)*64 + lane];
    v = fmaxf(v, 0.f);
    xout[(size_t)(gbase + nd)*64 + lane] = v;
    psum += v;
  }
  red[w][lane] = psum;
  __syncthreads();
  if (t < 64) {
    float s = 0.f;
    #pragma unroll
    for (int ww = 0; ww < 16; ++ww) s += red[ww][t];
    g_xs[g*384 + xs_off + t] = s * (1.f/512.f);
  }
}

// ============================================================================
// agg_full_use: loads the prebuilt CSR (no hist/scan/scatter), then gathers.
// ============================================================================
__global__ __launch_bounds__(1024)
void agg_full_use(int zr_idx, int xl_idx, int out_idx, int xs_off)
{
  __shared__ unsigned int hist[512], start[512];
  __shared__ unsigned short csr[EPG];
  __shared__ float red[16][64];
  const float* __restrict__ zr  = g_feat[zr_idx];
  const float* __restrict__ xlb = g_feat[xl_idx];
  float* __restrict__ xout = g_feat[out_idx];
  const int g = blockIdx.x, t = threadIdx.x;
  const int gbase = g * 512, ebase = g * EPG;
  if (t < 512) { hist[t] = g_deg[gbase + t]; start[t] = g_start[gbase + t]; }
  {
    const unsigned int* gcsr32 = reinterpret_cast<const unsigned int*>(&g_csr[ebase]);
    unsigned int* lcsr32 = reinterpret_cast<unsigned int*>(csr);
    for (int i = t; i < EPG/2; i += 1024) lcsr32[i] = gcsr32[i];
  }
  __syncthreads();
  const int lane = t & 63, w = t >> 6;
  const float* __restrict__ zlane = zr + (size_t)gbase * 64 + lane;
  float psum = 0.f;
  for (int nd = w; nd < 512; nd += 16) {
    const unsigned int s = start[nd], d = hist[nd];
    float a0 = 0.f, a1 = 0.f, a2 = 0.f, a3 = 0.f;
    unsigned int j = 0;
    for (; j + 4 <= d; j += 4) {
      const int i0 = csr[s+j], i1 = csr[s+j+1], i2 = csr[s+j+2], i3 = csr[s+j+3];
      const float v0 = zlane[(size_t)i0 * 64];
      const float v1 = zlane[(size_t)i1 * 64];
      const float v2 = zlane[(size_t)i2 * 64];
      const float v3 = zlane[(size_t)i3 * 64];
      a0 += v0; a1 += v1; a2 += v2; a3 += v3;
    }
    for (; j < d; ++j) a0 += zlane[(size_t)csr[s+j] * 64];
    const float acc = (a0 + a1) + (a2 + a3);
    float v = acc / (float)(d > 0 ? d : 1) + xlb[(size_t)(gbase + nd)*64 + lane];
    v = fmaxf(v, 0.f);
    xout[(size_t)(gbase + nd)*64 + lane] = v;
    psum += v;
  }
  red[w][lane] = psum;
  __syncthreads();
  if (t < 64) {
    float s = 0.f;
    #pragma unroll
    for (int ww = 0; ww < 16; ++ww) s += red[ww][t];
    g_xs[g*384 + xs_off + t] = s * (1.f/512.f);
  }
}

// ============================================================================
// SAG pool 0 (512 -> 57): CSR-based scalar aggregation (no LDS atomics).
// ============================================================================
__global__ __launch_bounds__(512)
void sag_pool0(int in_idx,
               const int* __restrict__ esrc, const int* __restrict__ edst,
               const float* __restrict__ wr, const float* __restrict__ wl,
               const float* __restrict__ pb,
               int xnew_idx, int out_stage)
{
  constexpr int NPER = 512, NPOW2 = 512, KSEL = 57;
  __shared__ float zs[NPER], swl[NPER], sscore[NPER];
  __shared__ unsigned long long keys[NPOW2];
  __shared__ unsigned short pcsr[EPG];
  __shared__ short newpos[NPER];
  __shared__ int scnt;
  const float* __restrict__ xin = g_feat[in_idx];
  float* __restrict__ xnew = g_feat[xnew_idx];
  int* __restrict__ eosrc = g_esrc[out_stage];
  int* __restrict__ eodst = g_edst[out_stage];
  const int g = blockIdx.x, t = threadIdx.x;
  const int gbase = g * NPER, ebase = g * EPG;
  const int lane = t & 63, w = t >> 6;            // 8 waves
  const float wrv = wr[lane], wlv = wl[lane];
  for (int nd = w; nd < NPER; nd += 8) {          // per-node dots via shfl reduce
    const float v = xin[(size_t)(gbase + nd)*64 + lane];
    float a = v * wrv, b = v * wlv;
    #pragma unroll
    for (int off = 32; off > 0; off >>= 1) {
      a += __shfl_xor(a, off);
      b += __shfl_xor(b, off);
    }
    if (lane == 0) { zs[nd] = a; swl[nd] = b; }
  }
  {
    const unsigned int* gcsr32 = reinterpret_cast<const unsigned int*>(&g_csr[ebase]);
    unsigned int* lcsr32 = reinterpret_cast<unsigned int*>(pcsr);
    for (int i = t; i < EPG/2; i += 512) lcsr32[i] = gcsr32[i];
  }
  if (t == 0) scnt = 0;
  __syncthreads();
  if (t < NPER) {                                  // CSR scalar gather
    const unsigned int s = g_start[gbase + t], d = g_deg[gbase + t];
    float a = 0.f;
    for (unsigned int j = 0; j < d; ++j) a += zs[pcsr[s + j]];
    sscore[t] = a / fmaxf((float)d, 1.f) + pb[0] + swl[t];
  }
  __syncthreads();
  if (t < NPOW2) {
    unsigned long long key = 0ull;
    if (t < NPER) {
      unsigned int u = __float_as_uint(sscore[t]);
      u = (u & 0x80000000u) ? ~u : (u | 0x80000000u);
      key = ((unsigned long long)u << 32) | (unsigned int)(~(unsigned int)t);
    }
    keys[t] = key;
  }
  __syncthreads();
  for (int kk = 2; kk <= NPOW2; kk <<= 1) {
    for (int j = kk >> 1; j > 0; j >>= 1) {
      if (t < NPOW2) {
        const int ixj = t ^ j;
        if (ixj > t) {
          const unsigned long long a = keys[t], bk = keys[ixj];
          const bool up = ((t & kk) == 0);
          if (up ? (a < bk) : (a > bk)) { keys[t] = bk; keys[ixj] = a; }
        }
      }
      __syncthreads();
    }
  }
  if (t < NPER) newpos[t] = -1;
  __syncthreads();
  if (t < KSEL)
    newpos[(int)(~(unsigned int)(keys[t] & 0xffffffffull))] = (short)t;
  __syncthreads();
  for (int r = w; r < KSEL; r += 8) {
    const int old = (int)(~(unsigned int)(keys[r] & 0xffffffffull));
    const float sc = tanhf(sscore[old]);
    xnew[(size_t)(g*KSEL + r)*64 + lane] =
        xin[(size_t)(gbase + old)*64 + lane] * sc;
  }
  for (int e = t; e < EPG; e += 512) {
    const int sl = esrc[ebase + e] - gbase;
    const int dl = edst[ebase + e] - gbase;
    const int ns = newpos[sl], nd2 = newpos[dl];
    if (ns >= 0 && nd2 >= 0) {
      const int slot = atomicAdd(&scnt, 1);
      eosrc[ebase + slot] = g*KSEL + ns;
      eodst[ebase + slot] = g*KSEL + nd2;
    }
  }
  __syncthreads();
  if (t == 0) g_ecnt[out_stage][g] = scnt;
}

// ============================================================================
// Fused tail: per graph, everything after pool0 (convs[1..4], pool1, gmp's).
// ============================================================================
__device__ __forceinline__ void conv_small(
    float* X, float* Z, float* ACC, float* w_s, const float* deg,
    const float* Wr, const float* Wl, const float* bias,
    int n, const int* esrc, const int* edst, int m, int gb, int ebase,
    int xs_off, int g, int t, int lane, int w)
{
  for (int i = t; i < n*64; i += 512) { Z[i] = 0.f; ACC[i] = 0.f; }
  __syncthreads();
  for (int kc = 0; kc < 4; ++kc) {
    for (int i = t; i < 1024; i += 512) w_s[i] = Wr[kc*1024 + i];
    __syncthreads();
    for (int r = w; r < n; r += 8) {
      float zacc = 0.f;
      #pragma unroll
      for (int k = 0; k < 16; ++k)
        zacc = fmaf(X[r*64 + kc*16 + k], w_s[k*64 + lane], zacc);
      Z[r*64 + lane] += zacc;
    }
    __syncthreads();
  }
  for (int e = w; e < m; e += 8) {
    const int sl = esrc[ebase + e] - gb;
    const int dl = edst[ebase + e] - gb;
    atomicAdd(&ACC[dl*64 + lane], Z[sl*64 + lane]);
  }
  __syncthreads();
  for (int i = t; i < n*64; i += 512) {
    const int r = i >> 6, f = i & 63;
    Z[i] = ACC[i] / fmaxf(deg[r], 1.f) + bias[f];
  }
  __syncthreads();
  for (int kc = 0; kc < 4; ++kc) {
    for (int i = t; i < 1024; i += 512) w_s[i] = Wl[kc*1024 + i];
    __syncthreads();
    for (int r = w; r < n; r += 8) {
      float zacc = 0.f;
      #pragma unroll
      for (int k = 0; k < 16; ++k)
        zacc = fmaf(X[r*64 + kc*16 + k], w_s[k*64 + lane], zacc);
      Z[r*64 + lane] += zacc;
    }
    __syncthreads();
  }
  for (int i = t; i < n*64; i += 512) X[i] = fmaxf(Z[i], 0.f);
  __syncthreads();
  if (t < 64) {
    float s = 0.f;
    for (int r = 0; r < n; ++r) s += X[r*64 + t];
    g_xs[g*384 + xs_off + t] = s / (float)n;
  }
  __syncthreads();
}

__global__ __launch_bounds__(512)
void tail(const float* __restrict__ cWr, const float* __restrict__ cWl,
          const float* __restrict__ cb,
          const float* __restrict__ pWr, const float* __restrict__ pWl,
          const float* __restrict__ pb)
{
  __shared__ float X[57*64], Z[57*64], ACC[57*64];   // 42.75 KB
  __shared__ float w_s[16*64];                       // 4 KB
  __shared__ float deg[64];
  __shared__ float zs[64], swl[64], sagg[64], sscore[64];
  __shared__ unsigned long long keys[64];
  __shared__ short newpos[64];
  __shared__ int scnt;
  const int g = blockIdx.x, t = threadIdx.x;
  const int lane = t & 63, w = t >> 6;
  const int ebase = g * EPG;

  for (int i = t; i < 57*64; i += 512) X[i] = g_feat[0][(size_t)(g*57)*64 + i];
  const int m0 = g_ecnt[0][g];
  if (t < 64) deg[t] = 0.f;
  __syncthreads();
  for (int e = t; e < m0; e += 512)
    atomicAdd(&deg[g_edst[0][ebase + e] - g*57], 1.f);
  __syncthreads();

  conv_small(X, Z, ACC, w_s, deg, cWr + 4096,  cWl + 4096,  cb + 64,
             57, g_esrc[0], g_edst[0], m0, g*57, ebase, 128, g, t, lane, w);
  conv_small(X, Z, ACC, w_s, deg, cWr + 8192,  cWl + 8192,  cb + 128,
             57, g_esrc[0], g_edst[0], m0, g*57, ebase, 192, g, t, lane, w);

  // ---- pool1: 57 -> 7 ----
  {
    const float pwrv = pWr[64 + lane], pwlv = pWl[64 + lane];
    for (int r = w; r < 57; r += 8) {
      float a = X[r*64 + lane] * pwrv, b = X[r*64 + lane] * pwlv;
      #pragma unroll
      for (int off = 32; off > 0; off >>= 1) {
        a += __shfl_xor(a, off);
        b += __shfl_xor(b, off);
      }
      if (lane == 0) { zs[r] = a; swl[r] = b; }
    }
    if (t < 64) sagg[t] = 0.f;
    if (t == 0) scnt = 0;
    __syncthreads();
    for (int e = t; e < m0; e += 512)
      atomicAdd(&sagg[g_edst[0][ebase + e] - g*57],
                zs[g_esrc[0][ebase + e] - g*57]);
    __syncthreads();
    if (t < 57) sscore[t] = sagg[t] / fmaxf(deg[t], 1.f) + pb[1] + swl[t];
    __syncthreads();
    if (t < 64) {
      unsigned long long key = 0ull;
      if (t < 57) {
        unsigned int u = __float_as_uint(sscore[t]);
        u = (u & 0x80000000u) ? ~u : (u | 0x80000000u);
        key = ((unsigned long long)u << 32) | (unsigned int)(~(unsigned int)t);
      }
      keys[t] = key;
    }
    __syncthreads();
    for (int kk = 2; kk <= 64; kk <<= 1) {
      for (int j = kk >> 1; j > 0; j >>= 1) {
        if (t < 64) {
          const int ixj = t ^ j;
          if (ixj > t) {
            const unsigned long long a = keys[t], bk = keys[ixj];
            const bool up = ((t & kk) == 0);
            if (up ? (a < bk) : (a > bk)) { keys[t] = bk; keys[ixj] = a; }
          }
        }
        __syncthreads();
      }
    }
    if (t < 64) newpos[t] = -1;
    __syncthreads();
    if (t < 7)
      newpos[(int)(~(unsigned int)(keys[t] & 0xffffffffull))] = (short)t;
    __syncthreads();
    for (int r = w; r < 7; r += 8) {
      const int old = (int)(~(unsigned int)(keys[r] & 0xffffffffull));
      const float sc = tanhf(sscore[old]);
      Z[r*64 + lane] = X[old*64 + lane] * sc;
    }
    for (int e = t; e < m0; e += 512) {
      const int sl = g_esrc[0][ebase + e] - g*57;
      const int dl = g_edst[0][ebase + e] - g*57;
      const int ns = newpos[sl], nd2 = newpos[dl];
      if (ns >= 0 && nd2 >= 0) {
        const int slot = atomicAdd(&scnt, 1);
        g_esrc[1][ebase + slot] = g*7 + ns;
        g_edst[1][ebase + slot] = g*7 + nd2;
      }
    }
    __syncthreads();
    for (int i = t; i < 7*64; i += 512) X[i] = Z[i];
    if (t < 64) deg[t] = 0.f;
    __syncthreads();
  }
  const int m1 = scnt;
  for (int e = t; e < m1; e += 512)
    atomicAdd(&deg[g_edst[1][ebase + e] - g*7], 1.f);
  __syncthreads();

  conv_small(X, Z, ACC, w_s, deg, cWr + 12288, cWl + 12288, cb + 192,
             7, g_esrc[1], g_edst[1], m1, g*7, ebase, 256, g, t, lane, w);
  conv_small(X, Z, ACC, w_s, deg, cWr + 16384, cWl + 16384, cb + 256,
             7, g_esrc[1], g_edst[1], m1, g*7, ebase, 320, g, t, lane, w);
}

// ============================================================================
// MLP head: h=[B,384] -> relu(h@W1+b1) -> @W2+b2 -> log_softmax
// ============================================================================
__global__ __launch_bounds__(64)
void head(const float* __restrict__ W1, const float* __restrict__ b1,
          const float* __restrict__ W2, const float* __restrict__ b2,
          float* __restrict__ out)
{
  __shared__ float h[384], o1[64], lg[2];
  const int g = blockIdx.x, t = threadIdx.x;
  for (int i = t; i < 384; i += 64) h[i] = g_xs[g*384 + i];
  __syncthreads();
  float acc = b1[t];
  for (int j = 0; j < 384; ++j) acc = fmaf(h[j], W1[j*64 + t], acc);
  o1[t] = fmaxf(acc, 0.f);
  __syncthreads();
  if (t < 2) {
    float a2 = b2[t];
    for (int f2 = 0; f2 < 64; ++f2) a2 = fmaf(o1[f2], W2[f2*2 + t], a2);
    lg[t] = a2;
  }
  __syncthreads();
  if (t < 2) {
    const float mx = fmaxf(lg[0], lg[1]);
    const float lse = mx + logf(expf(lg[0]-mx) + expf(lg[1]-mx));
    out[g*2 + t] = lg[t] - lse;
  }
}

// ============================================================================
extern "C" void kernel_launch(void* const* d_in, const int* in_sizes, int n_in,
                              void* d_out, int out_size, void* d_ws, size_t ws_size,
                              hipStream_t stream)
{
  (void)in_sizes; (void)n_in; (void)d_ws; (void)ws_size; (void)out_size;
  const float* x    = (const float*)d_in[0];
  const int*   ei   = (const int*)d_in[1];
  const float* c1Wr = (const float*)d_in[2];
  const float* c1Wl = (const float*)d_in[3];
  const float* c1b  = (const float*)d_in[4];
  const float* cWr  = (const float*)d_in[5];
  const float* cWl  = (const float*)d_in[6];
  const float* cb   = (const float*)d_in[7];
  const float* pWr  = (const float*)d_in[8];
  const float* pWl  = (const float*)d_in[9];
  const float* pb   = (const float*)d_in[10];
  const float* l1W  = (const float*)d_in[11];
  const float* l1b  = (const float*)d_in[12];
  const float* l2W  = (const float*)d_in[13];
  const float* l2b  = (const float*)d_in[14];
  float* out = (float*)d_out;
  const int* esrc = ei;
  const int* edst = ei + ETOT;

  // conv1 (160->64) + relu, xs[0]  (builds the shared CSR)
  mm_dual<160><<<NN0/64, 256, 0, stream>>>(x, -1, c1Wr, c1Wl, c1b, 0, 1);
  agg_full_build<<<NB, 1024, 0, stream>>>(0, 1, esrc, edst, 1, 0);
  // convs[0] + relu, xs[1]  (reuses CSR)
  mm_dual<64><<<NN0/64, 256, 0, stream>>>(nullptr, 1, cWr, cWl, cb, 0, 2);
  agg_full_use<<<NB, 1024, 0, stream>>>(0, 2, 2, 64);
  // pool0: 512 -> 57  (reuses CSR)
  sag_pool0<<<NB, 512, 0, stream>>>(2, esrc, edst, pWr, pWl, pb, 0, 0);
  // fused tail: convs[1..4] + pool1 + gmp's
  tail<<<NB, 512, 0, stream>>>(cWr, cWl, cb, pWr, pWl, pb);
  // head
  head<<<NB, 64, 0, stream>>>(l1W, l1b, l2W, l2b, out);
}

// Round 13
// 392.642 us; speedup vs baseline: 1.3420x; 1.0436x over previous
//
#include <hip/hip_runtime.h>
#include <math.h>

namespace {
constexpr int NB   = 256;          // graphs
constexpr int EPG  = 8192;         // edges per graph
constexpr int ETOT = NB * EPG;     // 2,097,152
constexpr int FH   = 64;           // hidden dim
constexpr int NN0  = NB * 512;     // 131072 nodes at full size
}

// ---- scratch (device globals: write-before-read each call, deterministic) ----
__device__ float g_feat[3][(size_t)NN0 * FH];   // rotating node-feature buffers
__device__ float g_xs[NB * 6 * FH];             // jumping-knowledge concat
__device__ int   g_esrc[2][ETOT];               // compacted edges (stage 0/1)
__device__ int   g_edst[2][ETOT];
__device__ int   g_ecnt[2][NB];
__device__ unsigned short g_csr[ETOT];          // shared CSR (built once/call)
__device__ unsigned int   g_deg[NN0], g_start[NN0];

// 8-wide gather chunk: 8 independent loads, 4 partial accumulators.
#define CH8(csr_, s_, j_, a0_, a1_, a2_, a3_)                                 \
  {                                                                           \
    const int i0 = csr_[s_ + j_ + 0], i1 = csr_[s_ + j_ + 1];                 \
    const int i2 = csr_[s_ + j_ + 2], i3 = csr_[s_ + j_ + 3];                 \
    const int i4 = csr_[s_ + j_ + 4], i5 = csr_[s_ + j_ + 5];                 \
    const int i6 = csr_[s_ + j_ + 6], i7 = csr_[s_ + j_ + 7];                 \
    const float v0 = zlane[(size_t)i0 * 64], v1 = zlane[(size_t)i1 * 64];     \
    const float v2 = zlane[(size_t)i2 * 64], v3 = zlane[(size_t)i3 * 64];     \
    const float v4 = zlane[(size_t)i4 * 64], v5 = zlane[(size_t)i5 * 64];     \
    const float v6 = zlane[(size_t)i6 * 64], v7 = zlane[(size_t)i7 * 64];     \
    a0_ += v0; a1_ += v1; a2_ += v2; a3_ += v3;                               \
    a0_ += v4; a1_ += v5; a2_ += v6; a3_ += v7;                               \
  }

// ============================================================================
// Dual matmul: zr = x@Wr ; xl = x@Wl + b   (v6: fmaf chains; plateau'd)
// ============================================================================
template<int K>
__global__ __launch_bounds__(256)
void mm_dual(const float* __restrict__ xext, int in_idx,
             const float* __restrict__ Wr, const float* __restrict__ Wl,
             const float* __restrict__ bias, int zr_idx, int xl_idx)
{
  constexpr int RPB = 64;           // rows per block
  constexpr int KC  = 32;           // k-chunk staged in LDS
  __shared__ float xs[RPB][KC];     // 8 KB
  __shared__ float wrT[KC/4][64][4];// 8 KB
  __shared__ float wlT[KC/4][64][4];// 8 KB
  const float* __restrict__ x = (in_idx < 0) ? xext : g_feat[in_idx];
  float* __restrict__ zr = g_feat[zr_idx];
  float* __restrict__ xl = g_feat[xl_idx];
  const int t = threadIdx.x;
  const int rowbase = blockIdx.x * RPB;
  const int f  = t & 31;
  const int rg = t >> 5;
  const int wv = t >> 6;
  const int wc = t & 63;
  const int wq = t >> 6;
  float ar0[8], ar1[8], al0[8], al1[8];
  #pragma unroll
  for (int r = 0; r < 8; ++r) { ar0[r]=0.f; ar1[r]=0.f; al0[r]=0.f; al1[r]=0.f; }

  for (int c = 0; c < K / KC; ++c) {
    __syncthreads();
    #pragma unroll
    for (int i = 0; i < 2; ++i) {
      const int idx = t + i * 256;
      const int r = idx >> 3, q = idx & 7;
      const float* gp = &x[(size_t)(rowbase + r) * K + c * KC + q * 4];
      float* lp = &xs[0][0] + (size_t)(i * 256 + wv * 64) * 4;
      __builtin_amdgcn_global_load_lds(
          (const __attribute__((address_space(1))) unsigned int*)gp,
          (__attribute__((address_space(3))) unsigned int*)lp, 16, 0, 0);
    }
    #pragma unroll
    for (int h = 0; h < 2; ++h) {
      const int kq = wq * 2 + h;
      #pragma unroll
      for (int i = 0; i < 4; ++i) {
        const int krow = c * KC + kq * 4 + i;
        wrT[kq][wc][i] = Wr[(size_t)krow * 64 + wc];
        wlT[kq][wc][i] = Wl[(size_t)krow * 64 + wc];
      }
    }
    __syncthreads();
    for (int k4 = 0; k4 < KC / 4; ++k4) {
      const float4 wr0 = *reinterpret_cast<const float4*>(&wrT[k4][f][0]);
      const float4 wr1 = *reinterpret_cast<const float4*>(&wrT[k4][f+32][0]);
      const float4 wl0 = *reinterpret_cast<const float4*>(&wlT[k4][f][0]);
      const float4 wl1 = *reinterpret_cast<const float4*>(&wlT[k4][f+32][0]);
      #pragma unroll
      for (int r = 0; r < 8; ++r) {
        const float4 xv = *reinterpret_cast<const float4*>(&xs[rg*8 + r][k4*4]);
        float a0 = ar0[r], a1 = ar1[r], b0 = al0[r], b1 = al1[r];
        a0 = fmaf(xv.x, wr0.x, a0); a0 = fmaf(xv.y, wr0.y, a0);
        a0 = fmaf(xv.z, wr0.z, a0); a0 = fmaf(xv.w, wr0.w, a0);
        a1 = fmaf(xv.x, wr1.x, a1); a1 = fmaf(xv.y, wr1.y, a1);
        a1 = fmaf(xv.z, wr1.z, a1); a1 = fmaf(xv.w, wr1.w, a1);
        b0 = fmaf(xv.x, wl0.x, b0); b0 = fmaf(xv.y, wl0.y, b0);
        b0 = fmaf(xv.z, wl0.z, b0); b0 = fmaf(xv.w, wl0.w, b0);
        b1 = fmaf(xv.x, wl1.x, b1); b1 = fmaf(xv.y, wl1.y, b1);
        b1 = fmaf(xv.z, wl1.z, b1); b1 = fmaf(xv.w, wl1.w, b1);
        ar0[r] = a0; ar1[r] = a1; al0[r] = b0; al1[r] = b1;
      }
    }
  }
  const float bv0 = bias[f], bv1 = bias[f + 32];
  #pragma unroll
  for (int r = 0; r < 8; ++r) {
    const size_t row = (size_t)(rowbase + rg * 8 + r);
    zr[row * 64 + f]      = ar0[r];
    zr[row * 64 + f + 32] = ar1[r];
    xl[row * 64 + f]      = al0[r] + bv0;
    xl[row * 64 + f + 32] = al1[r] + bv1;
  }
}

// ============================================================================
// Dual-node 8-unrolled gather + epilogue, shared by both agg kernels.
// Wave processes node pair (nd, nd+256): 16 independent loads in flight.
// ============================================================================
__device__ __forceinline__ float agg_gather_pair(
    const unsigned int* start, const unsigned int* hist,
    const unsigned short* csr, const float* __restrict__ zlane,
    const float* __restrict__ xlb, float* __restrict__ xout,
    int gbase, int w, int lane)
{
  float psum = 0.f;
  for (int nd = w; nd < 256; nd += 16) {
    const int ndA = nd, ndB = nd + 256;
    const unsigned int sA = start[ndA], dA = hist[ndA];
    const unsigned int sB = start[ndB], dB = hist[ndB];
    float aA0=0.f,aA1=0.f,aA2=0.f,aA3=0.f;
    float aB0=0.f,aB1=0.f,aB2=0.f,aB3=0.f;
    unsigned int jA = 0, jB = 0;
    while (jA + 8 <= dA && jB + 8 <= dB) {
      CH8(csr, sA, jA, aA0, aA1, aA2, aA3);
      CH8(csr, sB, jB, aB0, aB1, aB2, aB3);
      jA += 8; jB += 8;
    }
    while (jA + 8 <= dA) { CH8(csr, sA, jA, aA0, aA1, aA2, aA3); jA += 8; }
    while (jB + 8 <= dB) { CH8(csr, sB, jB, aB0, aB1, aB2, aB3); jB += 8; }
    for (; jA < dA; ++jA) aA0 += zlane[(size_t)csr[sA + jA] * 64];
    for (; jB < dB; ++jB) aB0 += zlane[(size_t)csr[sB + jB] * 64];
    const float accA = (aA0 + aA1) + (aA2 + aA3);
    const float accB = (aB0 + aB1) + (aB2 + aB3);
    float vA = accA / (float)(dA > 0 ? dA : 1) +
               xlb[(size_t)(gbase + ndA)*64 + lane];
    float vB = accB / (float)(dB > 0 ? dB : 1) +
               xlb[(size_t)(gbase + ndB)*64 + lane];
    vA = fmaxf(vA, 0.f);
    vB = fmaxf(vB, 0.f);
    xout[(size_t)(gbase + ndA)*64 + lane] = vA;
    xout[(size_t)(gbase + ndB)*64 + lane] = vB;
    psum += vA + vB;
  }
  return psum;
}

// ============================================================================
// agg_full_build: builds CSR in LDS, SAVES it, then dual-node gather + gmp.
// ============================================================================
__global__ __launch_bounds__(1024)
void agg_full_build(int zr_idx, int xl_idx,
                    const int* __restrict__ esrc, const int* __restrict__ edst,
                    int out_idx, int xs_off)
{
  __shared__ unsigned int hist[512], bufA[512], bufB[512];
  __shared__ unsigned short csr[EPG];
  __shared__ float red[16][64];
  const float* __restrict__ zr  = g_feat[zr_idx];
  const float* __restrict__ xlb = g_feat[xl_idx];
  float* __restrict__ xout = g_feat[out_idx];
  const int g = blockIdx.x, t = threadIdx.x;
  const int gbase = g * 512, ebase = g * EPG;
  for (int i = t; i < 512; i += 1024) hist[i] = 0;
  __syncthreads();
  for (int e = t; e < EPG; e += 1024)
    atomicAdd(&hist[edst[ebase + e] - gbase], 1u);
  __syncthreads();
  if (t < 512) bufA[t] = hist[t];
  __syncthreads();
  unsigned int *pa = bufA, *pb = bufB;
  for (int off = 1; off < 512; off <<= 1) {
    if (t < 512) {
      unsigned int v = pa[t];
      if (t >= off) v += pa[t - off];
      pb[t] = v;
    }
    __syncthreads();
    unsigned int* tmp = pa; pa = pb; pb = tmp;
  }
  unsigned int excl = 0;
  if (t < 512) excl = pa[t] - hist[t];
  __syncthreads();
  if (t < 512) { bufA[t] = excl; bufB[t] = excl; }
  __syncthreads();
  for (int e = t; e < EPG; e += 1024) {
    const int sl = esrc[ebase + e] - gbase;
    const int dl = edst[ebase + e] - gbase;
    const unsigned int pos = atomicAdd(&bufB[dl], 1u);
    csr[pos] = (unsigned short)sl;
  }
  __syncthreads();
  // persist CSR for downstream kernels
  if (t < 512) { g_deg[gbase + t] = hist[t]; g_start[gbase + t] = bufA[t]; }
  {
    unsigned int* gcsr32 = reinterpret_cast<unsigned int*>(&g_csr[ebase]);
    const unsigned int* lcsr32 = reinterpret_cast<const unsigned int*>(csr);
    for (int i = t; i < EPG/2; i += 1024) gcsr32[i] = lcsr32[i];
  }
  const int lane = t & 63, w = t >> 6;
  const float* __restrict__ zlane = zr + (size_t)gbase * 64 + lane;
  const float psum = agg_gather_pair(bufA, hist, csr, zlane, xlb, xout,
                                     gbase, w, lane);
  red[w][lane] = psum;
  __syncthreads();
  if (t < 64) {
    float s = 0.f;
    #pragma unroll
    for (int ww = 0; ww < 16; ++ww) s += red[ww][t];
    g_xs[g*384 + xs_off + t] = s * (1.f/512.f);
  }
}

// ============================================================================
// agg_full_use: loads prebuilt CSR, dual-node gather + gmp.
// ============================================================================
__global__ __launch_bounds__(1024)
void agg_full_use(int zr_idx, int xl_idx, int out_idx, int xs_off)
{
  __shared__ unsigned int hist[512], start[512];
  __shared__ unsigned short csr[EPG];
  __shared__ float red[16][64];
  const float* __restrict__ zr  = g_feat[zr_idx];
  const float* __restrict__ xlb = g_feat[xl_idx];
  float* __restrict__ xout = g_feat[out_idx];
  const int g = blockIdx.x, t = threadIdx.x;
  const int gbase = g * 512, ebase = g * EPG;
  if (t < 512) { hist[t] = g_deg[gbase + t]; start[t] = g_start[gbase + t]; }
  {
    const unsigned int* gcsr32 = reinterpret_cast<const unsigned int*>(&g_csr[ebase]);
    unsigned int* lcsr32 = reinterpret_cast<unsigned int*>(csr);
    for (int i = t; i < EPG/2; i += 1024) lcsr32[i] = gcsr32[i];
  }
  __syncthreads();
  const int lane = t & 63, w = t >> 6;
  const float* __restrict__ zlane = zr + (size_t)gbase * 64 + lane;
  const float psum = agg_gather_pair(start, hist, csr, zlane, xlb, xout,
                                     gbase, w, lane);
  red[w][lane] = psum;
  __syncthreads();
  if (t < 64) {
    float s = 0.f;
    #pragma unroll
    for (int ww = 0; ww < 16; ++ww) s += red[ww][t];
    g_xs[g*384 + xs_off + t] = s * (1.f/512.f);
  }
}

// ============================================================================
// SAG pool 0 (512 -> 57): CSR-based scalar aggregation (no LDS atomics).
// ============================================================================
__global__ __launch_bounds__(512)
void sag_pool0(int in_idx,
               const int* __restrict__ esrc, const int* __restrict__ edst,
               const float* __restrict__ wr, const float* __restrict__ wl,
               const float* __restrict__ pb,
               int xnew_idx, int out_stage)
{
  constexpr int NPER = 512, NPOW2 = 512, KSEL = 57;
  __shared__ float zs[NPER], swl[NPER], sscore[NPER];
  __shared__ unsigned long long keys[NPOW2];
  __shared__ unsigned short pcsr[EPG];
  __shared__ short newpos[NPER];
  __shared__ int scnt;
  const float* __restrict__ xin = g_feat[in_idx];
  float* __restrict__ xnew = g_feat[xnew_idx];
  int* __restrict__ eosrc = g_esrc[out_stage];
  int* __restrict__ eodst = g_edst[out_stage];
  const int g = blockIdx.x, t = threadIdx.x;
  const int gbase = g * NPER, ebase = g * EPG;
  const int lane = t & 63, w = t >> 6;            // 8 waves
  const float wrv = wr[lane], wlv = wl[lane];
  for (int nd = w; nd < NPER; nd += 8) {          // per-node dots via shfl reduce
    const float v = xin[(size_t)(gbase + nd)*64 + lane];
    float a = v * wrv, b = v * wlv;
    #pragma unroll
    for (int off = 32; off > 0; off >>= 1) {
      a += __shfl_xor(a, off);
      b += __shfl_xor(b, off);
    }
    if (lane == 0) { zs[nd] = a; swl[nd] = b; }
  }
  {
    const unsigned int* gcsr32 = reinterpret_cast<const unsigned int*>(&g_csr[ebase]);
    unsigned int* lcsr32 = reinterpret_cast<unsigned int*>(pcsr);
    for (int i = t; i < EPG/2; i += 512) lcsr32[i] = gcsr32[i];
  }
  if (t == 0) scnt = 0;
  __syncthreads();
  if (t < NPER) {                                  // CSR scalar gather
    const unsigned int s = g_start[gbase + t], d = g_deg[gbase + t];
    float a = 0.f;
    for (unsigned int j = 0; j < d; ++j) a += zs[pcsr[s + j]];
    sscore[t] = a / fmaxf((float)d, 1.f) + pb[0] + swl[t];
  }
  __syncthreads();
  if (t < NPOW2) {
    unsigned long long key = 0ull;
    if (t < NPER) {
      unsigned int u = __float_as_uint(sscore[t]);
      u = (u & 0x80000000u) ? ~u : (u | 0x80000000u);
      key = ((unsigned long long)u << 32) | (unsigned int)(~(unsigned int)t);
    }
    keys[t] = key;
  }
  __syncthreads();
  for (int kk = 2; kk <= NPOW2; kk <<= 1) {
    for (int j = kk >> 1; j > 0; j >>= 1) {
      if (t < NPOW2) {
        const int ixj = t ^ j;
        if (ixj > t) {
          const unsigned long long a = keys[t], bk = keys[ixj];
          const bool up = ((t & kk) == 0);
          if (up ? (a < bk) : (a > bk)) { keys[t] = bk; keys[ixj] = a; }
        }
      }
      __syncthreads();
    }
  }
  if (t < NPER) newpos[t] = -1;
  __syncthreads();
  if (t < KSEL)
    newpos[(int)(~(unsigned int)(keys[t] & 0xffffffffull))] = (short)t;
  __syncthreads();
  for (int r = w; r < KSEL; r += 8) {
    const int old = (int)(~(unsigned int)(keys[r] & 0xffffffffull));
    const float sc = tanhf(sscore[old]);
    xnew[(size_t)(g*KSEL + r)*64 + lane] =
        xin[(size_t)(gbase + old)*64 + lane] * sc;
  }
  for (int e = t; e < EPG; e += 512) {
    const int sl = esrc[ebase + e] - gbase;
    const int dl = edst[ebase + e] - gbase;
    const int ns = newpos[sl], nd2 = newpos[dl];
    if (ns >= 0 && nd2 >= 0) {
      const int slot = atomicAdd(&scnt, 1);
      eosrc[ebase + slot] = g*KSEL + ns;
      eodst[ebase + slot] = g*KSEL + nd2;
    }
  }
  __syncthreads();
  if (t == 0) g_ecnt[out_stage][g] = scnt;
}

// ============================================================================
// Fused tail: per graph, everything after pool0 (convs[1..4], pool1, gmp's).
// ============================================================================
__device__ __forceinline__ void conv_small(
    float* X, float* Z, float* ACC, float* w_s, const float* deg,
    const float* Wr, const float* Wl, const float* bias,
    int n, const int* esrc, const int* edst, int m, int gb, int ebase,
    int xs_off, int g, int t, int lane, int w)
{
  for (int i = t; i < n*64; i += 512) { Z[i] = 0.f; ACC[i] = 0.f; }
  __syncthreads();
  for (int kc = 0; kc < 4; ++kc) {
    for (int i = t; i < 1024; i += 512) w_s[i] = Wr[kc*1024 + i];
    __syncthreads();
    for (int r = w; r < n; r += 8) {
      float zacc = 0.f;
      #pragma unroll
      for (int k = 0; k < 16; ++k)
        zacc = fmaf(X[r*64 + kc*16 + k], w_s[k*64 + lane], zacc);
      Z[r*64 + lane] += zacc;
    }
    __syncthreads();
  }
  for (int e = w; e < m; e += 8) {
    const int sl = esrc[ebase + e] - gb;
    const int dl = edst[ebase + e] - gb;
    atomicAdd(&ACC[dl*64 + lane], Z[sl*64 + lane]);
  }
  __syncthreads();
  for (int i = t; i < n*64; i += 512) {
    const int r = i >> 6, f = i & 63;
    Z[i] = ACC[i] / fmaxf(deg[r], 1.f) + bias[f];
  }
  __syncthreads();
  for (int kc = 0; kc < 4; ++kc) {
    for (int i = t; i < 1024; i += 512) w_s[i] = Wl[kc*1024 + i];
    __syncthreads();
    for (int r = w; r < n; r += 8) {
      float zacc = 0.f;
      #pragma unroll
      for (int k = 0; k < 16; ++k)
        zacc = fmaf(X[r*64 + kc*16 + k], w_s[k*64 + lane], zacc);
      Z[r*64 + lane] += zacc;
    }
    __syncthreads();
  }
  for (int i = t; i < n*64; i += 512) X[i] = fmaxf(Z[i], 0.f);
  __syncthreads();
  if (t < 64) {
    float s = 0.f;
    for (int r = 0; r < n; ++r) s += X[r*64 + t];
    g_xs[g*384 + xs_off + t] = s / (float)n;
  }
  __syncthreads();
}

__global__ __launch_bounds__(512)
void tail(const float* __restrict__ cWr, const float* __restrict__ cWl,
          const float* __restrict__ cb,
          const float* __restrict__ pWr, const float* __restrict__ pWl,
          const float* __restrict__ pb)
{
  __shared__ float X[57*64], Z[57*64], ACC[57*64];   // 42.75 KB
  __shared__ float w_s[16*64];                       // 4 KB
  __shared__ float deg[64];
  __shared__ float zs[64], swl[64], sagg[64], sscore[64];
  __shared__ unsigned long long keys[64];
  __shared__ short newpos[64];
  __shared__ int scnt;
  const int g = blockIdx.x, t = threadIdx.x;
  const int lane = t & 63, w = t >> 6;
  const int ebase = g * EPG;

  for (int i = t; i < 57*64; i += 512) X[i] = g_feat[0][(size_t)(g*57)*64 + i];
  const int m0 = g_ecnt[0][g];
  if (t < 64) deg[t] = 0.f;
  __syncthreads();
  for (int e = t; e < m0; e += 512)
    atomicAdd(&deg[g_edst[0][ebase + e] - g*57], 1.f);
  __syncthreads();

  conv_small(X, Z, ACC, w_s, deg, cWr + 4096,  cWl + 4096,  cb + 64,
             57, g_esrc[0], g_edst[0], m0, g*57, ebase, 128, g, t, lane, w);
  conv_small(X, Z, ACC, w_s, deg, cWr + 8192,  cWl + 8192,  cb + 128,
             57, g_esrc[0], g_edst[0], m0, g*57, ebase, 192, g, t, lane, w);

  // ---- pool1: 57 -> 7 ----
  {
    const float pwrv = pWr[64 + lane], pwlv = pWl[64 + lane];
    for (int r = w; r < 57; r += 8) {
      float a = X[r*64 + lane] * pwrv, b = X[r*64 + lane] * pwlv;
      #pragma unroll
      for (int off = 32; off > 0; off >>= 1) {
        a += __shfl_xor(a, off);
        b += __shfl_xor(b, off);
      }
      if (lane == 0) { zs[r] = a; swl[r] = b; }
    }
    if (t < 64) sagg[t] = 0.f;
    if (t == 0) scnt = 0;
    __syncthreads();
    for (int e = t; e < m0; e += 512)
      atomicAdd(&sagg[g_edst[0][ebase + e] - g*57],
                zs[g_esrc[0][ebase + e] - g*57]);
    __syncthreads();
    if (t < 57) sscore[t] = sagg[t] / fmaxf(deg[t], 1.f) + pb[1] + swl[t];
    __syncthreads();
    if (t < 64) {
      unsigned long long key = 0ull;
      if (t < 57) {
        unsigned int u = __float_as_uint(sscore[t]);
        u = (u & 0x80000000u) ? ~u : (u | 0x80000000u);
        key = ((unsigned long long)u << 32) | (unsigned int)(~(unsigned int)t);
      }
      keys[t] = key;
    }
    __syncthreads();
    for (int kk = 2; kk <= 64; kk <<= 1) {
      for (int j = kk >> 1; j > 0; j >>= 1) {
        if (t < 64) {
          const int ixj = t ^ j;
          if (ixj > t) {
            const unsigned long long a = keys[t], bk = keys[ixj];
            const bool up = ((t & kk) == 0);
            if (up ? (a < bk) : (a > bk)) { keys[t] = bk; keys[ixj] = a; }
          }
        }
        __syncthreads();
      }
    }
    if (t < 64) newpos[t] = -1;
    __syncthreads();
    if (t < 7)
      newpos[(int)(~(unsigned int)(keys[t] & 0xffffffffull))] = (short)t;
    __syncthreads();
    for (int r = w; r < 7; r += 8) {
      const int old = (int)(~(unsigned int)(keys[r] & 0xffffffffull));
      const float sc = tanhf(sscore[old]);
      Z[r*64 + lane] = X[old*64 + lane] * sc;
    }
    for (int e = t; e < m0; e += 512) {
      const int sl = g_esrc[0][ebase + e] - g*57;
      const int dl = g_edst[0][ebase + e] - g*57;
      const int ns = newpos[sl], nd2 = newpos[dl];
      if (ns >= 0 && nd2 >= 0) {
        const int slot = atomicAdd(&scnt, 1);
        g_esrc[1][ebase + slot] = g*7 + ns;
        g_edst[1][ebase + slot] = g*7 + nd2;
      }
    }
    __syncthreads();
    for (int i = t; i < 7*64; i += 512) X[i] = Z[i];
    if (t < 64) deg[t] = 0.f;
    __syncthreads();
  }
  const int m1 = scnt;
  for (int e = t; e < m1; e += 512)
    atomicAdd(&deg[g_edst[1][ebase + e] - g*7], 1.f);
  __syncthreads();

  conv_small(X, Z, ACC, w_s, deg, cWr + 12288, cWl + 12288, cb + 192,
             7, g_esrc[1], g_edst[1], m1, g*7, ebase, 256, g, t, lane, w);
  conv_small(X, Z, ACC, w_s, deg, cWr + 16384, cWl + 16384, cb + 256,
             7, g_esrc[1], g_edst[1], m1, g*7, ebase, 320, g, t, lane, w);
}

// ============================================================================
// MLP head: h=[B,384] -> relu(h@W1+b1) -> @W2+b2 -> log_softmax
// ============================================================================
__global__ __launch_bounds__(64)
void head(const float* __restrict__ W1, const float* __restrict__ b1,
          const float* __restrict__ W2, const float* __restrict__ b2,
          float* __restrict__ out)
{
  __shared__ float h[384], o1[64], lg[2];
  const int g = blockIdx.x, t = threadIdx.x;
  for (int i = t; i < 384; i += 64) h[i] = g_xs[g*384 + i];
  __syncthreads();
  float acc = b1[t];
  for (int j = 0; j < 384; ++j) acc = fmaf(h[j], W1[j*64 + t], acc);
  o1[t] = fmaxf(acc, 0.f);
  __syncthreads();
  if (t < 2) {
    float a2 = b2[t];
    for (int f2 = 0; f2 < 64; ++f2) a2 = fmaf(o1[f2], W2[f2*2 + t], a2);
    lg[t] = a2;
  }
  __syncthreads();
  if (t < 2) {
    const float mx = fmaxf(lg[0], lg[1]);
    const float lse = mx + logf(expf(lg[0]-mx) + expf(lg[1]-mx));
    out[g*2 + t] = lg[t] - lse;
  }
}

// ============================================================================
extern "C" void kernel_launch(void* const* d_in, const int* in_sizes, int n_in,
                              void* d_out, int out_size, void* d_ws, size_t ws_size,
                              hipStream_t stream)
{
  (void)in_sizes; (void)n_in; (void)d_ws; (void)ws_size; (void)out_size;
  const float* x    = (const float*)d_in[0];
  const int*   ei   = (const int*)d_in[1];
  const float* c1Wr = (const float*)d_in[2];
  const float* c1Wl = (const float*)d_in[3];
  const float* c1b  = (const float*)d_in[4];
  const float* cWr  = (const float*)d_in[5];
  const float* cWl  = (const float*)d_in[6];
  const float* cb   = (const float*)d_in[7];
  const float* pWr  = (const float*)d_in[8];
  const float* pWl  = (const float*)d_in[9];
  const float* pb   = (const float*)d_in[10];
  const float* l1W  = (const float*)d_in[11];
  const float* l1b  = (const float*)d_in[12];
  const float* l2W  = (const float*)d_in[13];
  const float* l2b  = (const float*)d_in[14];
  float* out = (float*)d_out;
  const int* esrc = ei;
  const int* edst = ei + ETOT;

  // conv1 (160->64) + relu, xs[0]  (builds the shared CSR)
  mm_dual<160><<<NN0/64, 256, 0, stream>>>(x, -1, c1Wr, c1Wl, c1b, 0, 1);
  agg_full_build<<<NB, 1024, 0, stream>>>(0, 1, esrc, edst, 1, 0);
  // convs[0] + relu, xs[1]  (reuses CSR)
  mm_dual<64><<<NN0/64, 256, 0, stream>>>(nullptr, 1, cWr, cWl, cb, 0, 2);
  agg_full_use<<<NB, 1024, 0, stream>>>(0, 2, 2, 64);
  // pool0: 512 -> 57  (reuses CSR)
  sag_pool0<<<NB, 512, 0, stream>>>(2, esrc, edst, pWr, pWl, pb, 0, 0);
  // fused tail: convs[1..4] + pool1 + gmp's
  tail<<<NB, 512, 0, stream>>>(cWr, cWl, cb, pWr, pWl, pb);
  // head
  head<<<NB, 64, 0, stream>>>(l1W, l1b, l2W, l2b, out);
}

// Round 14
// 372.133 us; speedup vs baseline: 1.4160x; 1.0551x over previous
//
#include <hip/hip_runtime.h>
#include <math.h>

namespace {
constexpr int NB   = 256;          // graphs
constexpr int EPG  = 8192;         // edges per graph
constexpr int ETOT = NB * EPG;     // 2,097,152
constexpr int FH   = 64;           // hidden dim
constexpr int NN0  = NB * 512;     // 131072 nodes at full size
}

// ---- scratch (device globals: write-before-read each call, deterministic) ----
__device__ float g_feat[3][(size_t)NN0 * FH];   // rotating node-feature buffers
__device__ float g_xs[NB * 6 * FH];             // jumping-knowledge concat
__device__ int   g_esrc[2][ETOT];               // compacted edges (stage 0/1)
__device__ int   g_edst[2][ETOT];
__device__ int   g_ecnt[2][NB];
__device__ unsigned short g_csr[ETOT];          // shared CSR (built once/call)
__device__ unsigned int   g_deg[NN0], g_start[NN0];

// ============================================================================
// Dual matmul: zr = x@Wr ; xl = x@Wl + b   (v6: fmaf chains)
// ============================================================================
template<int K>
__global__ __launch_bounds__(256)
void mm_dual(const float* __restrict__ xext, int in_idx,
             const float* __restrict__ Wr, const float* __restrict__ Wl,
             const float* __restrict__ bias, int zr_idx, int xl_idx)
{
  constexpr int RPB = 64;           // rows per block
  constexpr int KC  = 32;           // k-chunk staged in LDS
  __shared__ float xs[RPB][KC];     // 8 KB
  __shared__ float wrT[KC/4][64][4];// 8 KB
  __shared__ float wlT[KC/4][64][4];// 8 KB
  const float* __restrict__ x = (in_idx < 0) ? xext : g_feat[in_idx];
  float* __restrict__ zr = g_feat[zr_idx];
  float* __restrict__ xl = g_feat[xl_idx];
  const int t = threadIdx.x;
  const int rowbase = blockIdx.x * RPB;
  const int f  = t & 31;
  const int rg = t >> 5;
  const int wv = t >> 6;
  const int wc = t & 63;
  const int wq = t >> 6;
  float ar0[8], ar1[8], al0[8], al1[8];
  #pragma unroll
  for (int r = 0; r < 8; ++r) { ar0[r]=0.f; ar1[r]=0.f; al0[r]=0.f; al1[r]=0.f; }

  for (int c = 0; c < K / KC; ++c) {
    __syncthreads();
    #pragma unroll
    for (int i = 0; i < 2; ++i) {
      const int idx = t + i * 256;
      const int r = idx >> 3, q = idx & 7;
      const float* gp = &x[(size_t)(rowbase + r) * K + c * KC + q * 4];
      float* lp = &xs[0][0] + (size_t)(i * 256 + wv * 64) * 4;
      __builtin_amdgcn_global_load_lds(
          (const __attribute__((address_space(1))) unsigned int*)gp,
          (__attribute__((address_space(3))) unsigned int*)lp, 16, 0, 0);
    }
    #pragma unroll
    for (int h = 0; h < 2; ++h) {
      const int kq = wq * 2 + h;
      #pragma unroll
      for (int i = 0; i < 4; ++i) {
        const int krow = c * KC + kq * 4 + i;
        wrT[kq][wc][i] = Wr[(size_t)krow * 64 + wc];
        wlT[kq][wc][i] = Wl[(size_t)krow * 64 + wc];
      }
    }
    __syncthreads();
    for (int k4 = 0; k4 < KC / 4; ++k4) {
      const float4 wr0 = *reinterpret_cast<const float4*>(&wrT[k4][f][0]);
      const float4 wr1 = *reinterpret_cast<const float4*>(&wrT[k4][f+32][0]);
      const float4 wl0 = *reinterpret_cast<const float4*>(&wlT[k4][f][0]);
      const float4 wl1 = *reinterpret_cast<const float4*>(&wlT[k4][f+32][0]);
      #pragma unroll
      for (int r = 0; r < 8; ++r) {
        const float4 xv = *reinterpret_cast<const float4*>(&xs[rg*8 + r][k4*4]);
        float a0 = ar0[r], a1 = ar1[r], b0 = al0[r], b1 = al1[r];
        a0 = fmaf(xv.x, wr0.x, a0); a0 = fmaf(xv.y, wr0.y, a0);
        a0 = fmaf(xv.z, wr0.z, a0); a0 = fmaf(xv.w, wr0.w, a0);
        a1 = fmaf(xv.x, wr1.x, a1); a1 = fmaf(xv.y, wr1.y, a1);
        a1 = fmaf(xv.z, wr1.z, a1); a1 = fmaf(xv.w, wr1.w, a1);
        b0 = fmaf(xv.x, wl0.x, b0); b0 = fmaf(xv.y, wl0.y, b0);
        b0 = fmaf(xv.z, wl0.z, b0); b0 = fmaf(xv.w, wl0.w, b0);
        b1 = fmaf(xv.x, wl1.x, b1); b1 = fmaf(xv.y, wl1.y, b1);
        b1 = fmaf(xv.z, wl1.z, b1); b1 = fmaf(xv.w, wl1.w, b1);
        ar0[r] = a0; ar1[r] = a1; al0[r] = b0; al1[r] = b1;
      }
    }
  }
  const float bv0 = bias[f], bv1 = bias[f + 32];
  #pragma unroll
  for (int r = 0; r < 8; ++r) {
    const size_t row = (size_t)(rowbase + rg * 8 + r);
    zr[row * 64 + f]      = ar0[r];
    zr[row * 64 + f + 32] = ar1[r];
    xl[row * 64 + f]      = al0[r] + bv0;
    xl[row * 64 + f + 32] = al1[r] + bv1;
  }
}

// ============================================================================
// agg_full_build v2: CSR build + zr slice staged in LDS (128 KB) ->
// gather is LDS-local conflict-free. 154 KB LDS, 1 block/CU.
// ============================================================================
__global__ __launch_bounds__(1024)
void agg_full_build(int zr_idx, int xl_idx,
                    const int* __restrict__ esrc, const int* __restrict__ edst,
                    int out_idx, int xs_off)
{
  __shared__ float zlds[512 * 64];                 // 128 KB
  __shared__ unsigned short csr[EPG];              // 16 KB
  __shared__ unsigned int hist[512], bufA[512], bufB[512];  // 6 KB
  __shared__ float red[16][64];                    // 4 KB   (total 154 KB)
  const float* __restrict__ zr  = g_feat[zr_idx];
  const float* __restrict__ xlb = g_feat[xl_idx];
  float* __restrict__ xout = g_feat[out_idx];
  const int g = blockIdx.x, t = threadIdx.x;
  const int gbase = g * 512, ebase = g * EPG;
  if (t < 512) hist[t] = 0;
  __syncthreads();
  // stage zr slice (coalesced) + edge histogram
  {
    const float4* zsrc = reinterpret_cast<const float4*>(zr + (size_t)gbase * 64);
    float4* zdst = reinterpret_cast<float4*>(zlds);
    #pragma unroll
    for (int i = 0; i < 8; ++i) zdst[t + i * 1024] = zsrc[t + i * 1024];
  }
  for (int e = t; e < EPG; e += 1024)
    atomicAdd(&hist[edst[ebase + e] - gbase], 1u);
  __syncthreads();
  if (t < 512) bufA[t] = hist[t];
  __syncthreads();
  unsigned int *pa = bufA, *pb = bufB;
  for (int off = 1; off < 512; off <<= 1) {
    if (t < 512) {
      unsigned int v = pa[t];
      if (t >= off) v += pa[t - off];
      pb[t] = v;
    }
    __syncthreads();
    unsigned int* tmp = pa; pa = pb; pb = tmp;
  }
  unsigned int excl = 0;
  if (t < 512) excl = pa[t] - hist[t];
  __syncthreads();
  if (t < 512) { bufA[t] = excl; bufB[t] = excl; }
  __syncthreads();
  for (int e = t; e < EPG; e += 1024) {
    const int sl = esrc[ebase + e] - gbase;
    const int dl = edst[ebase + e] - gbase;
    const unsigned int pos = atomicAdd(&bufB[dl], 1u);
    csr[pos] = (unsigned short)sl;
  }
  __syncthreads();
  // persist CSR for downstream kernels
  if (t < 512) { g_deg[gbase + t] = hist[t]; g_start[gbase + t] = bufA[t]; }
  {
    unsigned int* gcsr32 = reinterpret_cast<unsigned int*>(&g_csr[ebase]);
    const unsigned int* lcsr32 = reinterpret_cast<const unsigned int*>(csr);
    for (int i = t; i < EPG/2; i += 1024) gcsr32[i] = lcsr32[i];
  }
  const int lane = t & 63, w = t >> 6;
  float psum = 0.f;
  for (int nd = w; nd < 512; nd += 16) {
    const unsigned int s = bufA[nd], d = hist[nd];
    float a0 = 0.f, a1 = 0.f, a2 = 0.f, a3 = 0.f;
    unsigned int j = 0;
    for (; j + 4 <= d; j += 4) {
      const int i0 = csr[s+j], i1 = csr[s+j+1], i2 = csr[s+j+2], i3 = csr[s+j+3];
      a0 += zlds[i0*64 + lane]; a1 += zlds[i1*64 + lane];
      a2 += zlds[i2*64 + lane]; a3 += zlds[i3*64 + lane];
    }
    for (; j < d; ++j) a0 += zlds[csr[s+j]*64 + lane];
    const float acc = (a0 + a1) + (a2 + a3);
    float v = acc / (float)(d > 0 ? d : 1) + xlb[(size_t)(gbase + nd)*64 + lane];
    v = fmaxf(v, 0.f);
    xout[(size_t)(gbase + nd)*64 + lane] = v;
    psum += v;
  }
  red[w][lane] = psum;
  __syncthreads();
  if (t < 64) {
    float s = 0.f;
    #pragma unroll
    for (int ww = 0; ww < 16; ++ww) s += red[ww][t];
    g_xs[g*384 + xs_off + t] = s * (1.f/512.f);
  }
}

// ============================================================================
// agg_full_use v2: loads prebuilt CSR + zr slice into LDS, gathers locally.
// ============================================================================
__global__ __launch_bounds__(1024)
void agg_full_use(int zr_idx, int xl_idx, int out_idx, int xs_off)
{
  __shared__ float zlds[512 * 64];                 // 128 KB
  __shared__ unsigned short csr[EPG];              // 16 KB
  __shared__ unsigned int hist[512], start[512];   // 4 KB
  __shared__ float red[16][64];                    // 4 KB  (total 152 KB)
  const float* __restrict__ zr  = g_feat[zr_idx];
  const float* __restrict__ xlb = g_feat[xl_idx];
  float* __restrict__ xout = g_feat[out_idx];
  const int g = blockIdx.x, t = threadIdx.x;
  const int gbase = g * 512, ebase = g * EPG;
  if (t < 512) { hist[t] = g_deg[gbase + t]; start[t] = g_start[gbase + t]; }
  {
    const float4* zsrc = reinterpret_cast<const float4*>(zr + (size_t)gbase * 64);
    float4* zdst = reinterpret_cast<float4*>(zlds);
    #pragma unroll
    for (int i = 0; i < 8; ++i) zdst[t + i * 1024] = zsrc[t + i * 1024];
  }
  {
    const uint4* c4 = reinterpret_cast<const uint4*>(&g_csr[ebase]);  // 16 KB
    uint4* l4 = reinterpret_cast<uint4*>(csr);
    l4[t] = c4[t];                                 // 1024 x 16 B
  }
  __syncthreads();
  const int lane = t & 63, w = t >> 6;
  float psum = 0.f;
  for (int nd = w; nd < 512; nd += 16) {
    const unsigned int s = start[nd], d = hist[nd];
    float a0 = 0.f, a1 = 0.f, a2 = 0.f, a3 = 0.f;
    unsigned int j = 0;
    for (; j + 4 <= d; j += 4) {
      const int i0 = csr[s+j], i1 = csr[s+j+1], i2 = csr[s+j+2], i3 = csr[s+j+3];
      a0 += zlds[i0*64 + lane]; a1 += zlds[i1*64 + lane];
      a2 += zlds[i2*64 + lane]; a3 += zlds[i3*64 + lane];
    }
    for (; j < d; ++j) a0 += zlds[csr[s+j]*64 + lane];
    const float acc = (a0 + a1) + (a2 + a3);
    float v = acc / (float)(d > 0 ? d : 1) + xlb[(size_t)(gbase + nd)*64 + lane];
    v = fmaxf(v, 0.f);
    xout[(size_t)(gbase + nd)*64 + lane] = v;
    psum += v;
  }
  red[w][lane] = psum;
  __syncthreads();
  if (t < 64) {
    float s = 0.f;
    #pragma unroll
    for (int ww = 0; ww < 16; ++ww) s += red[ww][t];
    g_xs[g*384 + xs_off + t] = s * (1.f/512.f);
  }
}

// ============================================================================
// SAG pool 0 (512 -> 57): CSR-based scalar aggregation (no LDS atomics).
// ============================================================================
__global__ __launch_bounds__(512)
void sag_pool0(int in_idx,
               const int* __restrict__ esrc, const int* __restrict__ edst,
               const float* __restrict__ wr, const float* __restrict__ wl,
               const float* __restrict__ pb,
               int xnew_idx, int out_stage)
{
  constexpr int NPER = 512, NPOW2 = 512, KSEL = 57;
  __shared__ float zs[NPER], swl[NPER], sscore[NPER];
  __shared__ unsigned long long keys[NPOW2];
  __shared__ unsigned short pcsr[EPG];
  __shared__ short newpos[NPER];
  __shared__ int scnt;
  const float* __restrict__ xin = g_feat[in_idx];
  float* __restrict__ xnew = g_feat[xnew_idx];
  int* __restrict__ eosrc = g_esrc[out_stage];
  int* __restrict__ eodst = g_edst[out_stage];
  const int g = blockIdx.x, t = threadIdx.x;
  const int gbase = g * NPER, ebase = g * EPG;
  const int lane = t & 63, w = t >> 6;            // 8 waves
  const float wrv = wr[lane], wlv = wl[lane];
  for (int nd = w; nd < NPER; nd += 8) {          // per-node dots via shfl reduce
    const float v = xin[(size_t)(gbase + nd)*64 + lane];
    float a = v * wrv, b = v * wlv;
    #pragma unroll
    for (int off = 32; off > 0; off >>= 1) {
      a += __shfl_xor(a, off);
      b += __shfl_xor(b, off);
    }
    if (lane == 0) { zs[nd] = a; swl[nd] = b; }
  }
  {
    const unsigned int* gcsr32 = reinterpret_cast<const unsigned int*>(&g_csr[ebase]);
    unsigned int* lcsr32 = reinterpret_cast<unsigned int*>(pcsr);
    for (int i = t; i < EPG/2; i += 512) lcsr32[i] = gcsr32[i];
  }
  if (t == 0) scnt = 0;
  __syncthreads();
  if (t < NPER) {                                  // CSR scalar gather
    const unsigned int s = g_start[gbase + t], d = g_deg[gbase + t];
    float a = 0.f;
    for (unsigned int j = 0; j < d; ++j) a += zs[pcsr[s + j]];
    sscore[t] = a / fmaxf((float)d, 1.f) + pb[0] + swl[t];
  }
  __syncthreads();
  if (t < NPOW2) {
    unsigned long long key = 0ull;
    if (t < NPER) {
      unsigned int u = __float_as_uint(sscore[t]);
      u = (u & 0x80000000u) ? ~u : (u | 0x80000000u);
      key = ((unsigned long long)u << 32) | (unsigned int)(~(unsigned int)t);
    }
    keys[t] = key;
  }
  __syncthreads();
  for (int kk = 2; kk <= NPOW2; kk <<= 1) {
    for (int j = kk >> 1; j > 0; j >>= 1) {
      if (t < NPOW2) {
        const int ixj = t ^ j;
        if (ixj > t) {
          const unsigned long long a = keys[t], bk = keys[ixj];
          const bool up = ((t & kk) == 0);
          if (up ? (a < bk) : (a > bk)) { keys[t] = bk; keys[ixj] = a; }
        }
      }
      __syncthreads();
    }
  }
  if (t < NPER) newpos[t] = -1;
  __syncthreads();
  if (t < KSEL)
    newpos[(int)(~(unsigned int)(keys[t] & 0xffffffffull))] = (short)t;
  __syncthreads();
  for (int r = w; r < KSEL; r += 8) {
    const int old = (int)(~(unsigned int)(keys[r] & 0xffffffffull));
    const float sc = tanhf(sscore[old]);
    xnew[(size_t)(g*KSEL + r)*64 + lane] =
        xin[(size_t)(gbase + old)*64 + lane] * sc;
  }
  for (int e = t; e < EPG; e += 512) {
    const int sl = esrc[ebase + e] - gbase;
    const int dl = edst[ebase + e] - gbase;
    const int ns = newpos[sl], nd2 = newpos[dl];
    if (ns >= 0 && nd2 >= 0) {
      const int slot = atomicAdd(&scnt, 1);
      eosrc[ebase + slot] = g*KSEL + ns;
      eodst[ebase + slot] = g*KSEL + nd2;
    }
  }
  __syncthreads();
  if (t == 0) g_ecnt[out_stage][g] = scnt;
}

// ============================================================================
// Fused tail: per graph, everything after pool0 (convs[1..4], pool1, gmp's).
// ============================================================================
__device__ __forceinline__ void conv_small(
    float* X, float* Z, float* ACC, float* w_s, const float* deg,
    const float* Wr, const float* Wl, const float* bias,
    int n, const int* esrc, const int* edst, int m, int gb, int ebase,
    int xs_off, int g, int t, int lane, int w)
{
  for (int i = t; i < n*64; i += 512) { Z[i] = 0.f; ACC[i] = 0.f; }
  __syncthreads();
  for (int kc = 0; kc < 4; ++kc) {
    for (int i = t; i < 1024; i += 512) w_s[i] = Wr[kc*1024 + i];
    __syncthreads();
    for (int r = w; r < n; r += 8) {
      float zacc = 0.f;
      #pragma unroll
      for (int k = 0; k < 16; ++k)
        zacc = fmaf(X[r*64 + kc*16 + k], w_s[k*64 + lane], zacc);
      Z[r*64 + lane] += zacc;
    }
    __syncthreads();
  }
  for (int e = w; e < m; e += 8) {
    const int sl = esrc[ebase + e] - gb;
    const int dl = edst[ebase + e] - gb;
    atomicAdd(&ACC[dl*64 + lane], Z[sl*64 + lane]);
  }
  __syncthreads();
  for (int i = t; i < n*64; i += 512) {
    const int r = i >> 6, f = i & 63;
    Z[i] = ACC[i] / fmaxf(deg[r], 1.f) + bias[f];
  }
  __syncthreads();
  for (int kc = 0; kc < 4; ++kc) {
    for (int i = t; i < 1024; i += 512) w_s[i] = Wl[kc*1024 + i];
    __syncthreads();
    for (int r = w; r < n; r += 8) {
      float zacc = 0.f;
      #pragma unroll
      for (int k = 0; k < 16; ++k)
        zacc = fmaf(X[r*64 + kc*16 + k], w_s[k*64 + lane], zacc);
      Z[r*64 + lane] += zacc;
    }
    __syncthreads();
  }
  for (int i = t; i < n*64; i += 512) X[i] = fmaxf(Z[i], 0.f);
  __syncthreads();
  if (t < 64) {
    float s = 0.f;
    for (int r = 0; r < n; ++r) s += X[r*64 + t];
    g_xs[g*384 + xs_off + t] = s / (float)n;
  }
  __syncthreads();
}

__global__ __launch_bounds__(512)
void tail(const float* __restrict__ cWr, const float* __restrict__ cWl,
          const float* __restrict__ cb,
          const float* __restrict__ pWr, const float* __restrict__ pWl,
          const float* __restrict__ pb)
{
  __shared__ float X[57*64], Z[57*64], ACC[57*64];   // 42.75 KB
  __shared__ float w_s[16*64];                       // 4 KB
  __shared__ float deg[64];
  __shared__ float zs[64], swl[64], sagg[64], sscore[64];
  __shared__ unsigned long long keys[64];
  __shared__ short newpos[64];
  __shared__ int scnt;
  const int g = blockIdx.x, t = threadIdx.x;
  const int lane = t & 63, w = t >> 6;
  const int ebase = g * EPG;

  for (int i = t; i < 57*64; i += 512) X[i] = g_feat[0][(size_t)(g*57)*64 + i];
  const int m0 = g_ecnt[0][g];
  if (t < 64) deg[t] = 0.f;
  __syncthreads();
  for (int e = t; e < m0; e += 512)
    atomicAdd(&deg[g_edst[0][ebase + e] - g*57], 1.f);
  __syncthreads();

  conv_small(X, Z, ACC, w_s, deg, cWr + 4096,  cWl + 4096,  cb + 64,
             57, g_esrc[0], g_edst[0], m0, g*57, ebase, 128, g, t, lane, w);
  conv_small(X, Z, ACC, w_s, deg, cWr + 8192,  cWl + 8192,  cb + 128,
             57, g_esrc[0], g_edst[0], m0, g*57, ebase, 192, g, t, lane, w);

  // ---- pool1: 57 -> 7 ----
  {
    const float pwrv = pWr[64 + lane], pwlv = pWl[64 + lane];
    for (int r = w; r < 57; r += 8) {
      float a = X[r*64 + lane] * pwrv, b = X[r*64 + lane] * pwlv;
      #pragma unroll
      for (int off = 32; off > 0; off >>= 1) {
        a += __shfl_xor(a, off);
        b += __shfl_xor(b, off);
      }
      if (lane == 0) { zs[r] = a; swl[r] = b; }
    }
    if (t < 64) sagg[t] = 0.f;
    if (t == 0) scnt = 0;
    __syncthreads();
    for (int e = t; e < m0; e += 512)
      atomicAdd(&sagg[g_edst[0][ebase + e] - g*57],
                zs[g_esrc[0][ebase + e] - g*57]);
    __syncthreads();
    if (t < 57) sscore[t] = sagg[t] / fmaxf(deg[t], 1.f) + pb[1] + swl[t];
    __syncthreads();
    if (t < 64) {
      unsigned long long key = 0ull;
      if (t < 57) {
        unsigned int u = __float_as_uint(sscore[t]);
        u = (u & 0x80000000u) ? ~u : (u | 0x80000000u);
        key = ((unsigned long long)u << 32) | (unsigned int)(~(unsigned int)t);
      }
      keys[t] = key;
    }
    __syncthreads();
    for (int kk = 2; kk <= 64; kk <<= 1) {
      for (int j = kk >> 1; j > 0; j >>= 1) {
        if (t < 64) {
          const int ixj = t ^ j;
          if (ixj > t) {
            const unsigned long long a = keys[t], bk = keys[ixj];
            const bool up = ((t & kk) == 0);
            if (up ? (a < bk) : (a > bk)) { keys[t] = bk; keys[ixj] = a; }
          }
        }
        __syncthreads();
      }
    }
    if (t < 64) newpos[t] = -1;
    __syncthreads();
    if (t < 7)
      newpos[(int)(~(unsigned int)(keys[t] & 0xffffffffull))] = (short)t;
    __syncthreads();
    for (int r = w; r < 7; r += 8) {
      const int old = (int)(~(unsigned int)(keys[r] & 0xffffffffull));
      const float sc = tanhf(sscore[old]);
      Z[r*64 + lane] = X[old*64 + lane] * sc;
    }
    for (int e = t; e < m0; e += 512) {
      const int sl = g_esrc[0][ebase + e] - g*57;
      const int dl = g_edst[0][ebase + e] - g*57;
      const int ns = newpos[sl], nd2 = newpos[dl];
      if (ns >= 0 && nd2 >= 0) {
        const int slot = atomicAdd(&scnt, 1);
        g_esrc[1][ebase + slot] = g*7 + ns;
        g_edst[1][ebase + slot] = g*7 + nd2;
      }
    }
    __syncthreads();
    for (int i = t; i < 7*64; i += 512) X[i] = Z[i];
    if (t < 64) deg[t] = 0.f;
    __syncthreads();
  }
  const int m1 = scnt;
  for (int e = t; e < m1; e += 512)
    atomicAdd(&deg[g_edst[1][ebase + e] - g*7], 1.f);
  __syncthreads();

  conv_small(X, Z, ACC, w_s, deg, cWr + 12288, cWl + 12288, cb + 192,
             7, g_esrc[1], g_edst[1], m1, g*7, ebase, 256, g, t, lane, w);
  conv_small(X, Z, ACC, w_s, deg, cWr + 16384, cWl + 16384, cb + 256,
             7, g_esrc[1], g_edst[1], m1, g*7, ebase, 320, g, t, lane, w);
}

// ============================================================================
// MLP head: h=[B,384] -> relu(h@W1+b1) -> @W2+b2 -> log_softmax
// ============================================================================
__global__ __launch_bounds__(64)
void head(const float* __restrict__ W1, const float* __restrict__ b1,
          const float* __restrict__ W2, const float* __restrict__ b2,
          float* __restrict__ out)
{
  __shared__ float h[384], o1[64], lg[2];
  const int g = blockIdx.x, t = threadIdx.x;
  for (int i = t; i < 384; i += 64) h[i] = g_xs[g*384 + i];
  __syncthreads();
  float acc = b1[t];
  for (int j = 0; j < 384; ++j) acc = fmaf(h[j], W1[j*64 + t], acc);
  o1[t] = fmaxf(acc, 0.f);
  __syncthreads();
  if (t < 2) {
    float a2 = b2[t];
    for (int f2 = 0; f2 < 64; ++f2) a2 = fmaf(o1[f2], W2[f2*2 + t], a2);
    lg[t] = a2;
  }
  __syncthreads();
  if (t < 2) {
    const float mx = fmaxf(lg[0], lg[1]);
    const float lse = mx + logf(expf(lg[0]-mx) + expf(lg[1]-mx));
    out[g*2 + t] = lg[t] - lse;
  }
}

// ============================================================================
extern "C" void kernel_launch(void* const* d_in, const int* in_sizes, int n_in,
                              void* d_out, int out_size, void* d_ws, size_t ws_size,
                              hipStream_t stream)
{
  (void)in_sizes; (void)n_in; (void)d_ws; (void)ws_size; (void)out_size;
  const float* x    = (const float*)d_in[0];
  const int*   ei   = (const int*)d_in[1];
  const float* c1Wr = (const float*)d_in[2];
  const float* c1Wl = (const float*)d_in[3];
  const float* c1b  = (const float*)d_in[4];
  const float* cWr  = (const float*)d_in[5];
  const float* cWl  = (const float*)d_in[6];
  const float* cb   = (const float*)d_in[7];
  const float* pWr  = (const float*)d_in[8];
  const float* pWl  = (const float*)d_in[9];
  const float* pb   = (const float*)d_in[10];
  const float* l1W  = (const float*)d_in[11];
  const float* l1b  = (const float*)d_in[12];
  const float* l2W  = (const float*)d_in[13];
  const float* l2b  = (const float*)d_in[14];
  float* out = (float*)d_out;
  const int* esrc = ei;
  const int* edst = ei + ETOT;

  // conv1 (160->64) + relu, xs[0]  (builds the shared CSR)
  mm_dual<160><<<NN0/64, 256, 0, stream>>>(x, -1, c1Wr, c1Wl, c1b, 0, 1);
  agg_full_build<<<NB, 1024, 0, stream>>>(0, 1, esrc, edst, 1, 0);
  // convs[0] + relu, xs[1]  (reuses CSR)
  mm_dual<64><<<NN0/64, 256, 0, stream>>>(nullptr, 1, cWr, cWl, cb, 0, 2);
  agg_full_use<<<NB, 1024, 0, stream>>>(0, 2, 2, 64);
  // pool0: 512 -> 57  (reuses CSR)
  sag_pool0<<<NB, 512, 0, stream>>>(2, esrc, edst, pWr, pWl, pb, 0, 0);
  // fused tail: convs[1..4] + pool1 + gmp's
  tail<<<NB, 512, 0, stream>>>(cWr, cWl, cb, pWr, pWl, pb);
  // head
  head<<<NB, 64, 0, stream>>>(l1W, l1b, l2W, l2b, out);
}

// Round 15
// 367.477 us; speedup vs baseline: 1.4339x; 1.0127x over previous
//
#include <hip/hip_runtime.h>
#include <math.h>

namespace {
constexpr int NB   = 256;          // graphs
constexpr int EPG  = 8192;         // edges per graph
constexpr int ETOT = NB * EPG;     // 2,097,152
constexpr int FH   = 64;           // hidden dim
constexpr int NN0  = NB * 512;     // 131072 nodes at full size
}

// ---- scratch (device globals: write-before-read each call, deterministic) ----
__device__ float g_feat[3][(size_t)NN0 * FH];   // rotating node-feature buffers
__device__ float g_xs[NB * 6 * FH];             // jumping-knowledge concat
__device__ int   g_esrc[2][ETOT];               // compacted edges (stage 0/1)
__device__ int   g_edst[2][ETOT];
__device__ int   g_ecnt[2][NB];
__device__ unsigned short g_csr[ETOT];          // shared CSR (built once/call)
__device__ unsigned int   g_deg[NN0], g_start[NN0];

// ============================================================================
// Dual matmul: zr = x@Wr ; xl = x@Wl + b
// v7: RPB=128 (16 rows/thread) to halve staging+barrier overhead per output.
// k4 loop pinned no-unroll (v3 lesson: unroll -> weight-load hoist -> spill).
// ============================================================================
template<int K>
__global__ __launch_bounds__(256)
void mm_dual(const float* __restrict__ xext, int in_idx,
             const float* __restrict__ Wr, const float* __restrict__ Wl,
             const float* __restrict__ bias, int zr_idx, int xl_idx)
{
  constexpr int RPB = 128;          // rows per block
  constexpr int KC  = 32;           // k-chunk staged in LDS
  __shared__ float xs[RPB][KC];     // 16 KB
  __shared__ float wrT[KC/4][64][4];// 8 KB
  __shared__ float wlT[KC/4][64][4];// 8 KB
  const float* __restrict__ x = (in_idx < 0) ? xext : g_feat[in_idx];
  float* __restrict__ zr = g_feat[zr_idx];
  float* __restrict__ xl = g_feat[xl_idx];
  const int t = threadIdx.x;
  const int rowbase = blockIdx.x * RPB;
  const int f  = t & 31;
  const int rg = t >> 5;            // 8 row-groups x 16 rows
  const int wv = t >> 6;
  const int wc = t & 63;
  const int wq = t >> 6;
  float ar0[16], ar1[16], al0[16], al1[16];
  #pragma unroll
  for (int r = 0; r < 16; ++r) { ar0[r]=0.f; ar1[r]=0.f; al0[r]=0.f; al1[r]=0.f; }

  for (int c = 0; c < K / KC; ++c) {
    __syncthreads();
    #pragma unroll
    for (int i = 0; i < 4; ++i) {          // x: 1024 slots of 16B = 16 KB
      const int idx = t + i * 256;
      const int r = idx >> 3, q = idx & 7;
      const float* gp = &x[(size_t)(rowbase + r) * K + c * KC + q * 4];
      float* lp = &xs[0][0] + (size_t)(i * 256 + wv * 64) * 4;
      __builtin_amdgcn_global_load_lds(
          (const __attribute__((address_space(1))) unsigned int*)gp,
          (__attribute__((address_space(3))) unsigned int*)lp, 16, 0, 0);
    }
    #pragma unroll
    for (int h = 0; h < 2; ++h) {
      const int kq = wq * 2 + h;
      #pragma unroll
      for (int i = 0; i < 4; ++i) {
        const int krow = c * KC + kq * 4 + i;
        wrT[kq][wc][i] = Wr[(size_t)krow * 64 + wc];
        wlT[kq][wc][i] = Wl[(size_t)krow * 64 + wc];
      }
    }
    __syncthreads();
    #pragma unroll 1
    for (int k4 = 0; k4 < KC / 4; ++k4) {
      const float4 wr0 = *reinterpret_cast<const float4*>(&wrT[k4][f][0]);
      const float4 wr1 = *reinterpret_cast<const float4*>(&wrT[k4][f+32][0]);
      const float4 wl0 = *reinterpret_cast<const float4*>(&wlT[k4][f][0]);
      const float4 wl1 = *reinterpret_cast<const float4*>(&wlT[k4][f+32][0]);
      #pragma unroll
      for (int r = 0; r < 16; ++r) {
        const float4 xv = *reinterpret_cast<const float4*>(&xs[rg*16 + r][k4*4]);
        float a0 = ar0[r], a1 = ar1[r], b0 = al0[r], b1 = al1[r];
        a0 = fmaf(xv.x, wr0.x, a0); a0 = fmaf(xv.y, wr0.y, a0);
        a0 = fmaf(xv.z, wr0.z, a0); a0 = fmaf(xv.w, wr0.w, a0);
        a1 = fmaf(xv.x, wr1.x, a1); a1 = fmaf(xv.y, wr1.y, a1);
        a1 = fmaf(xv.z, wr1.z, a1); a1 = fmaf(xv.w, wr1.w, a1);
        b0 = fmaf(xv.x, wl0.x, b0); b0 = fmaf(xv.y, wl0.y, b0);
        b0 = fmaf(xv.z, wl0.z, b0); b0 = fmaf(xv.w, wl0.w, b0);
        b1 = fmaf(xv.x, wl1.x, b1); b1 = fmaf(xv.y, wl1.y, b1);
        b1 = fmaf(xv.z, wl1.z, b1); b1 = fmaf(xv.w, wl1.w, b1);
        ar0[r] = a0; ar1[r] = a1; al0[r] = b0; al1[r] = b1;
      }
    }
  }
  const float bv0 = bias[f], bv1 = bias[f + 32];
  #pragma unroll
  for (int r = 0; r < 16; ++r) {
    const size_t row = (size_t)(rowbase + rg * 16 + r);
    zr[row * 64 + f]      = ar0[r];
    zr[row * 64 + f + 32] = ar1[r];
    xl[row * 64 + f]      = al0[r] + bv0;
    xl[row * 64 + f + 32] = al1[r] + bv1;
  }
}

// ============================================================================
// agg_full_build: CSR build + zr staged in LDS; gather LDS-local. (round 14)
// ============================================================================
__global__ __launch_bounds__(1024)
void agg_full_build(int zr_idx, int xl_idx,
                    const int* __restrict__ esrc, const int* __restrict__ edst,
                    int out_idx, int xs_off)
{
  __shared__ float zlds[512 * 64];                 // 128 KB
  __shared__ unsigned short csr[EPG];              // 16 KB
  __shared__ unsigned int hist[512], bufA[512], bufB[512];  // 6 KB
  __shared__ float red[16][64];                    // 4 KB
  const float* __restrict__ zr  = g_feat[zr_idx];
  const float* __restrict__ xlb = g_feat[xl_idx];
  float* __restrict__ xout = g_feat[out_idx];
  const int g = blockIdx.x, t = threadIdx.x;
  const int gbase = g * 512, ebase = g * EPG;
  if (t < 512) hist[t] = 0;
  __syncthreads();
  {
    const float4* zsrc = reinterpret_cast<const float4*>(zr + (size_t)gbase * 64);
    float4* zdst = reinterpret_cast<float4*>(zlds);
    #pragma unroll
    for (int i = 0; i < 8; ++i) zdst[t + i * 1024] = zsrc[t + i * 1024];
  }
  for (int e = t; e < EPG; e += 1024)
    atomicAdd(&hist[edst[ebase + e] - gbase], 1u);
  __syncthreads();
  if (t < 512) bufA[t] = hist[t];
  __syncthreads();
  unsigned int *pa = bufA, *pb = bufB;
  for (int off = 1; off < 512; off <<= 1) {
    if (t < 512) {
      unsigned int v = pa[t];
      if (t >= off) v += pa[t - off];
      pb[t] = v;
    }
    __syncthreads();
    unsigned int* tmp = pa; pa = pb; pb = tmp;
  }
  unsigned int excl = 0;
  if (t < 512) excl = pa[t] - hist[t];
  __syncthreads();
  if (t < 512) { bufA[t] = excl; bufB[t] = excl; }
  __syncthreads();
  for (int e = t; e < EPG; e += 1024) {
    const int sl = esrc[ebase + e] - gbase;
    const int dl = edst[ebase + e] - gbase;
    const unsigned int pos = atomicAdd(&bufB[dl], 1u);
    csr[pos] = (unsigned short)sl;
  }
  __syncthreads();
  if (t < 512) { g_deg[gbase + t] = hist[t]; g_start[gbase + t] = bufA[t]; }
  {
    unsigned int* gcsr32 = reinterpret_cast<unsigned int*>(&g_csr[ebase]);
    const unsigned int* lcsr32 = reinterpret_cast<const unsigned int*>(csr);
    for (int i = t; i < EPG/2; i += 1024) gcsr32[i] = lcsr32[i];
  }
  const int lane = t & 63, w = t >> 6;
  float psum = 0.f;
  for (int nd = w; nd < 512; nd += 16) {
    const unsigned int s = bufA[nd], d = hist[nd];
    float a0 = 0.f, a1 = 0.f, a2 = 0.f, a3 = 0.f;
    unsigned int j = 0;
    for (; j + 4 <= d; j += 4) {
      const int i0 = csr[s+j], i1 = csr[s+j+1], i2 = csr[s+j+2], i3 = csr[s+j+3];
      a0 += zlds[i0*64 + lane]; a1 += zlds[i1*64 + lane];
      a2 += zlds[i2*64 + lane]; a3 += zlds[i3*64 + lane];
    }
    for (; j < d; ++j) a0 += zlds[csr[s+j]*64 + lane];
    const float acc = (a0 + a1) + (a2 + a3);
    float v = acc / (float)(d > 0 ? d : 1) + xlb[(size_t)(gbase + nd)*64 + lane];
    v = fmaxf(v, 0.f);
    xout[(size_t)(gbase + nd)*64 + lane] = v;
    psum += v;
  }
  red[w][lane] = psum;
  __syncthreads();
  if (t < 64) {
    float s = 0.f;
    #pragma unroll
    for (int ww = 0; ww < 16; ++ww) s += red[ww][t];
    g_xs[g*384 + xs_off + t] = s * (1.f/512.f);
  }
}

// ============================================================================
// conv_agg_fused: replaces mm_dual<64>(full) + agg_full_use.
// Per graph: stage X1 (128KB) + CSR; z2/xl2 = X1@{Wr,Wl} in registers (wave
// owns 32 contiguous rows; x-rows via wave-uniform broadcast b128); write z2
// back in place; LDS-local gather; relu+bias+gmp. 159.7 KB LDS.
// ============================================================================
__global__ __launch_bounds__(1024)
void conv_agg_fused(int x_idx, const float* __restrict__ Wr,
                    const float* __restrict__ Wl, const float* __restrict__ bias,
                    int out_idx, int xs_off)
{
  __shared__ float zlds[512 * 64];                 // 128 KB: X1, then z2
  __shared__ unsigned short csr[EPG];              // 16 KB
  __shared__ unsigned int hist[512], start[512];   // 4 KB
  __shared__ float w_r[1024], w_l[1024];           // 8 KB
  const float* __restrict__ X1 = g_feat[x_idx];
  float* __restrict__ xout = g_feat[out_idx];
  const int g = blockIdx.x, t = threadIdx.x;
  const int gbase = g * 512, ebase = g * EPG;
  const int lane = t & 63, w = t >> 6;             // 16 waves
  // stage X1 slice + CSR + deg/start
  {
    const float4* src = reinterpret_cast<const float4*>(X1 + (size_t)gbase * 64);
    float4* dst = reinterpret_cast<float4*>(zlds);
    #pragma unroll
    for (int i = 0; i < 8; ++i) dst[t + i * 1024] = src[t + i * 1024];
  }
  if (t < 512) { hist[t] = g_deg[gbase + t]; start[t] = g_start[gbase + t]; }
  {
    const uint4* c4 = reinterpret_cast<const uint4*>(&g_csr[ebase]);
    uint4* l4 = reinterpret_cast<uint4*>(csr);
    l4[t] = c4[t];
  }
  // GEMM: wave w owns rows [w*32, w*32+32)
  const int ndbase = w * 32;
  float zacc[32], xla[32];
  #pragma unroll
  for (int i = 0; i < 32; ++i) { zacc[i] = 0.f; xla[i] = 0.f; }
  #pragma unroll 1
  for (int c = 0; c < 4; ++c) {                    // 16-wide k chunks
    __syncthreads();                               // (1st iter: staging done)
    w_r[t] = Wr[c * 1024 + t];
    w_l[t] = Wl[c * 1024 + t];
    __syncthreads();
    #pragma unroll 1
    for (int k4 = 0; k4 < 4; ++k4) {
      const int kb = k4 * 4;
      const float wr0 = w_r[(kb+0)*64 + lane], wr1 = w_r[(kb+1)*64 + lane],
                  wr2 = w_r[(kb+2)*64 + lane], wr3 = w_r[(kb+3)*64 + lane];
      const float wl0 = w_l[(kb+0)*64 + lane], wl1 = w_l[(kb+1)*64 + lane],
                  wl2 = w_l[(kb+2)*64 + lane], wl3 = w_l[(kb+3)*64 + lane];
      #pragma unroll
      for (int i = 0; i < 32; ++i) {
        const float4 xv = *reinterpret_cast<const float4*>(
            &zlds[(ndbase + i) * 64 + c * 16 + kb]);
        float za = zacc[i], xa = xla[i];
        za = fmaf(xv.x, wr0, za); za = fmaf(xv.y, wr1, za);
        za = fmaf(xv.z, wr2, za); za = fmaf(xv.w, wr3, za);
        xa = fmaf(xv.x, wl0, xa); xa = fmaf(xv.y, wl1, xa);
        xa = fmaf(xv.z, wl2, xa); xa = fmaf(xv.w, wl3, xa);
        zacc[i] = za; xla[i] = xa;
      }
    }
  }
  __syncthreads();                                 // all X1 reads complete
  #pragma unroll
  for (int i = 0; i < 32; ++i)
    zlds[(ndbase + i) * 64 + lane] = zacc[i];      // z2 in place
  __syncthreads();
  // gather + epilogue
  const float bv = bias[lane];
  float psum = 0.f;
  #pragma unroll 1
  for (int i = 0; i < 32; ++i) {
    const int nd = ndbase + i;
    const unsigned int s = start[nd], d = hist[nd];
    float a0 = 0.f, a1 = 0.f, a2 = 0.f, a3 = 0.f;
    unsigned int j = 0;
    for (; j + 4 <= d; j += 4) {
      const int i0 = csr[s+j], i1 = csr[s+j+1], i2 = csr[s+j+2], i3 = csr[s+j+3];
      a0 += zlds[i0*64 + lane]; a1 += zlds[i1*64 + lane];
      a2 += zlds[i2*64 + lane]; a3 += zlds[i3*64 + lane];
    }
    for (; j < d; ++j) a0 += zlds[csr[s+j]*64 + lane];
    float v = ((a0 + a1) + (a2 + a3)) / (float)(d > 0 ? d : 1) + xla[i] + bv;
    v = fmaxf(v, 0.f);
    xout[(size_t)(gbase + nd)*64 + lane] = v;
    psum += v;
  }
  __syncthreads();                                 // zlds free now
  zlds[w * 64 + lane] = psum;
  __syncthreads();
  if (t < 64) {
    float s = 0.f;
    #pragma unroll
    for (int ww = 0; ww < 16; ++ww) s += zlds[ww*64 + t];
    g_xs[g*384 + xs_off + t] = s * (1.f/512.f);
  }
}

// ============================================================================
// SAG pool 0 (512 -> 57): CSR-based scalar aggregation (no LDS atomics).
// ============================================================================
__global__ __launch_bounds__(512)
void sag_pool0(int in_idx,
               const int* __restrict__ esrc, const int* __restrict__ edst,
               const float* __restrict__ wr, const float* __restrict__ wl,
               const float* __restrict__ pb,
               int xnew_idx, int out_stage)
{
  constexpr int NPER = 512, NPOW2 = 512, KSEL = 57;
  __shared__ float zs[NPER], swl[NPER], sscore[NPER];
  __shared__ unsigned long long keys[NPOW2];
  __shared__ unsigned short pcsr[EPG];
  __shared__ short newpos[NPER];
  __shared__ int scnt;
  const float* __restrict__ xin = g_feat[in_idx];
  float* __restrict__ xnew = g_feat[xnew_idx];
  int* __restrict__ eosrc = g_esrc[out_stage];
  int* __restrict__ eodst = g_edst[out_stage];
  const int g = blockIdx.x, t = threadIdx.x;
  const int gbase = g * NPER, ebase = g * EPG;
  const int lane = t & 63, w = t >> 6;            // 8 waves
  const float wrv = wr[lane], wlv = wl[lane];
  for (int nd = w; nd < NPER; nd += 8) {
    const float v = xin[(size_t)(gbase + nd)*64 + lane];
    float a = v * wrv, b = v * wlv;
    #pragma unroll
    for (int off = 32; off > 0; off >>= 1) {
      a += __shfl_xor(a, off);
      b += __shfl_xor(b, off);
    }
    if (lane == 0) { zs[nd] = a; swl[nd] = b; }
  }
  {
    const unsigned int* gcsr32 = reinterpret_cast<const unsigned int*>(&g_csr[ebase]);
    unsigned int* lcsr32 = reinterpret_cast<unsigned int*>(pcsr);
    for (int i = t; i < EPG/2; i += 512) lcsr32[i] = gcsr32[i];
  }
  if (t == 0) scnt = 0;
  __syncthreads();
  if (t < NPER) {
    const unsigned int s = g_start[gbase + t], d = g_deg[gbase + t];
    float a = 0.f;
    for (unsigned int j = 0; j < d; ++j) a += zs[pcsr[s + j]];
    sscore[t] = a / fmaxf((float)d, 1.f) + pb[0] + swl[t];
  }
  __syncthreads();
  if (t < NPOW2) {
    unsigned long long key = 0ull;
    if (t < NPER) {
      unsigned int u = __float_as_uint(sscore[t]);
      u = (u & 0x80000000u) ? ~u : (u | 0x80000000u);
      key = ((unsigned long long)u << 32) | (unsigned int)(~(unsigned int)t);
    }
    keys[t] = key;
  }
  __syncthreads();
  for (int kk = 2; kk <= NPOW2; kk <<= 1) {
    for (int j = kk >> 1; j > 0; j >>= 1) {
      if (t < NPOW2) {
        const int ixj = t ^ j;
        if (ixj > t) {
          const unsigned long long a = keys[t], bk = keys[ixj];
          const bool up = ((t & kk) == 0);
          if (up ? (a < bk) : (a > bk)) { keys[t] = bk; keys[ixj] = a; }
        }
      }
      __syncthreads();
    }
  }
  if (t < NPER) newpos[t] = -1;
  __syncthreads();
  if (t < KSEL)
    newpos[(int)(~(unsigned int)(keys[t] & 0xffffffffull))] = (short)t;
  __syncthreads();
  for (int r = w; r < KSEL; r += 8) {
    const int old = (int)(~(unsigned int)(keys[r] & 0xffffffffull));
    const float sc = tanhf(sscore[old]);
    xnew[(size_t)(g*KSEL + r)*64 + lane] =
        xin[(size_t)(gbase + old)*64 + lane] * sc;
  }
  for (int e = t; e < EPG; e += 512) {
    const int sl = esrc[ebase + e] - gbase;
    const int dl = edst[ebase + e] - gbase;
    const int ns = newpos[sl], nd2 = newpos[dl];
    if (ns >= 0 && nd2 >= 0) {
      const int slot = atomicAdd(&scnt, 1);
      eosrc[ebase + slot] = g*KSEL + ns;
      eodst[ebase + slot] = g*KSEL + nd2;
    }
  }
  __syncthreads();
  if (t == 0) g_ecnt[out_stage][g] = scnt;
}

// ============================================================================
// Fused tail: per graph, everything after pool0 (convs[1..4], pool1, gmp's).
// ============================================================================
__device__ __forceinline__ void conv_small(
    float* X, float* Z, float* ACC, float* w_s, const float* deg,
    const float* Wr, const float* Wl, const float* bias,
    int n, const int* esrc, const int* edst, int m, int gb, int ebase,
    int xs_off, int g, int t, int lane, int w)
{
  for (int i = t; i < n*64; i += 512) { Z[i] = 0.f; ACC[i] = 0.f; }
  __syncthreads();
  for (int kc = 0; kc < 4; ++kc) {
    for (int i = t; i < 1024; i += 512) w_s[i] = Wr[kc*1024 + i];
    __syncthreads();
    for (int r = w; r < n; r += 8) {
      float zacc = 0.f;
      #pragma unroll
      for (int k = 0; k < 16; ++k)
        zacc = fmaf(X[r*64 + kc*16 + k], w_s[k*64 + lane], zacc);
      Z[r*64 + lane] += zacc;
    }
    __syncthreads();
  }
  for (int e = w; e < m; e += 8) {
    const int sl = esrc[ebase + e] - gb;
    const int dl = edst[ebase + e] - gb;
    atomicAdd(&ACC[dl*64 + lane], Z[sl*64 + lane]);
  }
  __syncthreads();
  for (int i = t; i < n*64; i += 512) {
    const int r = i >> 6, f = i & 63;
    Z[i] = ACC[i] / fmaxf(deg[r], 1.f) + bias[f];
  }
  __syncthreads();
  for (int kc = 0; kc < 4; ++kc) {
    for (int i = t; i < 1024; i += 512) w_s[i] = Wl[kc*1024 + i];
    __syncthreads();
    for (int r = w; r < n; r += 8) {
      float zacc = 0.f;
      #pragma unroll
      for (int k = 0; k < 16; ++k)
        zacc = fmaf(X[r*64 + kc*16 + k], w_s[k*64 + lane], zacc);
      Z[r*64 + lane] += zacc;
    }
    __syncthreads();
  }
  for (int i = t; i < n*64; i += 512) X[i] = fmaxf(Z[i], 0.f);
  __syncthreads();
  if (t < 64) {
    float s = 0.f;
    for (int r = 0; r < n; ++r) s += X[r*64 + t];
    g_xs[g*384 + xs_off + t] = s / (float)n;
  }
  __syncthreads();
}

__global__ __launch_bounds__(512)
void tail(const float* __restrict__ cWr, const float* __restrict__ cWl,
          const float* __restrict__ cb,
          const float* __restrict__ pWr, const float* __restrict__ pWl,
          const float* __restrict__ pb)
{
  __shared__ float X[57*64], Z[57*64], ACC[57*64];   // 42.75 KB
  __shared__ float w_s[16*64];                       // 4 KB
  __shared__ float deg[64];
  __shared__ float zs[64], swl[64], sagg[64], sscore[64];
  __shared__ unsigned long long keys[64];
  __shared__ short newpos[64];
  __shared__ int scnt;
  const int g = blockIdx.x, t = threadIdx.x;
  const int lane = t & 63, w = t >> 6;
  const int ebase = g * EPG;

  for (int i = t; i < 57*64; i += 512) X[i] = g_feat[0][(size_t)(g*57)*64 + i];
  const int m0 = g_ecnt[0][g];
  if (t < 64) deg[t] = 0.f;
  __syncthreads();
  for (int e = t; e < m0; e += 512)
    atomicAdd(&deg[g_edst[0][ebase + e] - g*57], 1.f);
  __syncthreads();

  conv_small(X, Z, ACC, w_s, deg, cWr + 4096,  cWl + 4096,  cb + 64,
             57, g_esrc[0], g_edst[0], m0, g*57, ebase, 128, g, t, lane, w);
  conv_small(X, Z, ACC, w_s, deg, cWr + 8192,  cWl + 8192,  cb + 128,
             57, g_esrc[0], g_edst[0], m0, g*57, ebase, 192, g, t, lane, w);

  // ---- pool1: 57 -> 7 ----
  {
    const float pwrv = pWr[64 + lane], pwlv = pWl[64 + lane];
    for (int r = w; r < 57; r += 8) {
      float a = X[r*64 + lane] * pwrv, b = X[r*64 + lane] * pwlv;
      #pragma unroll
      for (int off = 32; off > 0; off >>= 1) {
        a += __shfl_xor(a, off);
        b += __shfl_xor(b, off);
      }
      if (lane == 0) { zs[r] = a; swl[r] = b; }
    }
    if (t < 64) sagg[t] = 0.f;
    if (t == 0) scnt = 0;
    __syncthreads();
    for (int e = t; e < m0; e += 512)
      atomicAdd(&sagg[g_edst[0][ebase + e] - g*57],
                zs[g_esrc[0][ebase + e] - g*57]);
    __syncthreads();
    if (t < 57) sscore[t] = sagg[t] / fmaxf(deg[t], 1.f) + pb[1] + swl[t];
    __syncthreads();
    if (t < 64) {
      unsigned long long key = 0ull;
      if (t < 57) {
        unsigned int u = __float_as_uint(sscore[t]);
        u = (u & 0x80000000u) ? ~u : (u | 0x80000000u);
        key = ((unsigned long long)u << 32) | (unsigned int)(~(unsigned int)t);
      }
      keys[t] = key;
    }
    __syncthreads();
    for (int kk = 2; kk <= 64; kk <<= 1) {
      for (int j = kk >> 1; j > 0; j >>= 1) {
        if (t < 64) {
          const int ixj = t ^ j;
          if (ixj > t) {
            const unsigned long long a = keys[t], bk = keys[ixj];
            const bool up = ((t & kk) == 0);
            if (up ? (a < bk) : (a > bk)) { keys[t] = bk; keys[ixj] = a; }
          }
        }
        __syncthreads();
      }
    }
    if (t < 64) newpos[t] = -1;
    __syncthreads();
    if (t < 7)
      newpos[(int)(~(unsigned int)(keys[t] & 0xffffffffull))] = (short)t;
    __syncthreads();
    for (int r = w; r < 7; r += 8) {
      const int old = (int)(~(unsigned int)(keys[r] & 0xffffffffull));
      const float sc = tanhf(sscore[old]);
      Z[r*64 + lane] = X[old*64 + lane] * sc;
    }
    for (int e = t; e < m0; e += 512) {
      const int sl = g_esrc[0][ebase + e] - g*57;
      const int dl = g_edst[0][ebase + e] - g*57;
      const int ns = newpos[sl], nd2 = newpos[dl];
      if (ns >= 0 && nd2 >= 0) {
        const int slot = atomicAdd(&scnt, 1);
        g_esrc[1][ebase + slot] = g*7 + ns;
        g_edst[1][ebase + slot] = g*7 + nd2;
      }
    }
    __syncthreads();
    for (int i = t; i < 7*64; i += 512) X[i] = Z[i];
    if (t < 64) deg[t] = 0.f;
    __syncthreads();
  }
  const int m1 = scnt;
  for (int e = t; e < m1; e += 512)
    atomicAdd(&deg[g_edst[1][ebase + e] - g*7], 1.f);
  __syncthreads();

  conv_small(X, Z, ACC, w_s, deg, cWr + 12288, cWl + 12288, cb + 192,
             7, g_esrc[1], g_edst[1], m1, g*7, ebase, 256, g, t, lane, w);
  conv_small(X, Z, ACC, w_s, deg, cWr + 16384, cWl + 16384, cb + 256,
             7, g_esrc[1], g_edst[1], m1, g*7, ebase, 320, g, t, lane, w);
}

// ============================================================================
// MLP head: h=[B,384] -> relu(h@W1+b1) -> @W2+b2 -> log_softmax
// ============================================================================
__global__ __launch_bounds__(64)
void head(const float* __restrict__ W1, const float* __restrict__ b1,
          const float* __restrict__ W2, const float* __restrict__ b2,
          float* __restrict__ out)
{
  __shared__ float h[384], o1[64], lg[2];
  const int g = blockIdx.x, t = threadIdx.x;
  for (int i = t; i < 384; i += 64) h[i] = g_xs[g*384 + i];
  __syncthreads();
  float acc = b1[t];
  for (int j = 0; j < 384; ++j) acc = fmaf(h[j], W1[j*64 + t], acc);
  o1[t] = fmaxf(acc, 0.f);
  __syncthreads();
  if (t < 2) {
    float a2 = b2[t];
    for (int f2 = 0; f2 < 64; ++f2) a2 = fmaf(o1[f2], W2[f2*2 + t], a2);
    lg[t] = a2;
  }
  __syncthreads();
  if (t < 2) {
    const float mx = fmaxf(lg[0], lg[1]);
    const float lse = mx + logf(expf(lg[0]-mx) + expf(lg[1]-mx));
    out[g*2 + t] = lg[t] - lse;
  }
}

// ============================================================================
extern "C" void kernel_launch(void* const* d_in, const int* in_sizes, int n_in,
                              void* d_out, int out_size, void* d_ws, size_t ws_size,
                              hipStream_t stream)
{
  (void)in_sizes; (void)n_in; (void)d_ws; (void)ws_size; (void)out_size;
  const float* x    = (const float*)d_in[0];
  const int*   ei   = (const int*)d_in[1];
  const float* c1Wr = (const float*)d_in[2];
  const float* c1Wl = (const float*)d_in[3];
  const float* c1b  = (const float*)d_in[4];
  const float* cWr  = (const float*)d_in[5];
  const float* cWl  = (const float*)d_in[6];
  const float* cb   = (const float*)d_in[7];
  const float* pWr  = (const float*)d_in[8];
  const float* pWl  = (const float*)d_in[9];
  const float* pb   = (const float*)d_in[10];
  const float* l1W  = (const float*)d_in[11];
  const float* l1b  = (const float*)d_in[12];
  const float* l2W  = (const float*)d_in[13];
  const float* l2b  = (const float*)d_in[14];
  float* out = (float*)d_out;
  const int* esrc = ei;
  const int* edst = ei + ETOT;

  // conv1 (160->64) + relu, xs[0]  (builds the shared CSR)
  mm_dual<160><<<NN0/128, 256, 0, stream>>>(x, -1, c1Wr, c1Wl, c1b, 0, 1);
  agg_full_build<<<NB, 1024, 0, stream>>>(0, 1, esrc, edst, 1, 0);
  // convs[0] + relu, xs[1]  (fused GEMM + aggregation, reuses CSR)
  conv_agg_fused<<<NB, 1024, 0, stream>>>(1, cWr, cWl, cb, 2, 64);
  // pool0: 512 -> 57  (reuses CSR)
  sag_pool0<<<NB, 512, 0, stream>>>(2, esrc, edst, pWr, pWl, pb, 0, 0);
  // fused tail: convs[1..4] + pool1 + gmp's
  tail<<<NB, 512, 0, stream>>>(cWr, cWl, cb, pWr, pWl, pb);
  // head
  head<<<NB, 64, 0, stream>>>(l1W, l1b, l2W, l2b, out);
}